// Round 6
// baseline (389.321 us; speedup 1.0000x reference)
//
#include <hip/hip_runtime.h>
#include <stdint.h>

// MultiHeadedAttention: B=2,S=2048,D=1024,H=16,HD=64
// R6: attn = 8-wave blocks with IN-BLOCK KV-SPLIT (waves 0-3: kv[0,1024),
// waves 4-7: kv[1024,2048); additive max-free partials combined via LDS) ->
// 16 waves/CU. Plus mask-zero tile-skip flags (atomicOr in mask_prep; zero
// mask => zero atomics) eliminating mask loads/unpack/adds per skipped tile.
// Keeps R5's 32x32x16 MFMA, in-reg P (cvt_pk+permlane32_swap), LDS K/V dbuf.
// Workspace: 0 qb/vT, 8 kb/x, 16 vb/mb0, 24 w3, 30 wo, 32 qh, 40 kh,
//            48 vh/mb1, 56 flags(4KB)

typedef __bf16 bf16x8 __attribute__((ext_vector_type(8)));
typedef __bf16 bf16x4 __attribute__((ext_vector_type(4)));
typedef float f32x4 __attribute__((ext_vector_type(4)));
typedef float f32x16 __attribute__((ext_vector_type(16)));
typedef unsigned u32x4 __attribute__((ext_vector_type(4)));

static constexpr float L2E  = 1.4426950408889634f;
static constexpr float QSCL = 0.18033688011112042f;   // 0.125 * log2(e)
static constexpr float GELC = -2.4554669595930157f;   // -1.702 * log2(e)

__device__ __forceinline__ void async_load16(const void* g, void* l) {
    __builtin_amdgcn_global_load_lds(
        (const __attribute__((address_space(1))) unsigned int*)(uintptr_t)g,
        (__attribute__((address_space(3))) unsigned int*)(unsigned int)(uintptr_t)l,
        16, 0, 0);
}

// Stage ROWS x 64-bf16 tile into LDS, phys = row*128 + (kb ^ ((row&7)<<4)).
template <int ROWS>
__device__ __forceinline__ void stage_tile(const __bf16* g, int ld, __bf16* lds, int tid) {
#pragma unroll
    for (int r = 0; r < ROWS / 32; ++r) {
        int p = r * 4096 + tid * 16;
        int row = p >> 7;
        int kbp = p & 127;
        int kbl = kbp ^ ((row & 7) << 4);
        async_load16((const char*)(g + (size_t)row * ld) + kbl,
                     (char*)lds + (p & ~1023));
    }
}

__device__ __forceinline__ bf16x8 lds_frag(const __bf16* base, int row, int kb) {
    return *(const bf16x8*)((const char*)base + (row << 7) + (kb ^ ((row & 7) << 4)));
}

__device__ __forceinline__ unsigned cvtpk(float a, float b) {
    unsigned d;
    asm("v_cvt_pk_bf16_f32 %0, %1, %2" : "=v"(d) : "v"(a), "v"(b));
    return d;
}
__device__ __forceinline__ void pswap(unsigned& a, unsigned& b) {
    asm("v_permlane32_swap_b32 %0, %1" : "+v"(a), "+v"(b));
}

// ---------------- prep kernels ----------------

__global__ __launch_bounds__(256) void cvt3_kernel(const float* __restrict__ q,
                                                   const float* __restrict__ k,
                                                   const float* __restrict__ v,
                                                   __bf16* __restrict__ qb,
                                                   __bf16* __restrict__ kb,
                                                   __bf16* __restrict__ vb) {
    int z = blockIdx.y;
    const float* src = z == 0 ? q : (z == 1 ? k : v);
    __bf16* dst = z == 0 ? qb : (z == 1 ? kb : vb);
    int i = blockIdx.x * 256 + threadIdx.x;
    f32x4 val = ((const f32x4*)src)[i];
    bf16x4 o;
    o[0] = (__bf16)val[0]; o[1] = (__bf16)val[1];
    o[2] = (__bf16)val[2]; o[3] = (__bf16)val[3];
    ((bf16x4*)dst)[i] = o;
}

__global__ __launch_bounds__(256) void flags_init(unsigned* __restrict__ flags) {
    int t = threadIdx.x;
#pragma unroll
    for (int k = 0; k < 4; ++k) flags[t + k * 256] = 0u;
}

// mask f32 -> bf16 pre-scaled by log2(e); split per batch; set nonzero flags
// per (b, q/128, kv/64) tile via atomicOr (zero mask => zero atomic traffic).
__global__ __launch_bounds__(256) void mask_prep(const float* __restrict__ m,
                                                 __bf16* __restrict__ mb0,
                                                 __bf16* __restrict__ mb1,
                                                 unsigned* __restrict__ flags) {
    int b = blockIdx.y;
    const f32x4* src = (const f32x4*)(m + (size_t)b * 4194304);
    __bf16* dst = b ? mb1 : mb0;
    int i = blockIdx.x * 256 + threadIdx.x;
    f32x4 val = src[i];
    bf16x4 o;
    o[0] = (__bf16)(val[0] * L2E); o[1] = (__bf16)(val[1] * L2E);
    o[2] = (__bf16)(val[2] * L2E); o[3] = (__bf16)(val[3] * L2E);
    ((bf16x4*)dst)[i] = o;
    bool nz = (val[0] != 0.f) | (val[1] != 0.f) | (val[2] != 0.f) | (val[3] != 0.f);
    if (nz) {
        int i4 = i * 4;
        int q = i4 >> 11, kv = i4 & 2047;
        atomicOr(flags + ((b * 16 + (q >> 7)) * 32 + (kv >> 6)), 1u);
    }
}

__global__ __launch_bounds__(256) void pack_wqkv(const float* __restrict__ Wq,
                                                 const float* __restrict__ Wk,
                                                 const float* __restrict__ Wv,
                                                 __bf16* __restrict__ out) {
    __shared__ __bf16 T[64][72];
    int tid = threadIdx.x;
    int k0 = blockIdx.x * 64, h = blockIdx.y, z = blockIdx.z;
    const float* W = z == 0 ? Wq : (z == 1 ? Wk : Wv);
#pragma unroll
    for (int it = 0; it < 4; ++it) {
        int idx = it * 1024 + tid * 4;
        int r = idx >> 6, e = idx & 63;
        f32x4 val = *(const f32x4*)(W + ((size_t)h * 1024 + k0 + r) * 64 + e);
#pragma unroll
        for (int j = 0; j < 4; ++j) T[r][e + j] = (__bf16)val[j];
    }
    __syncthreads();
    int e2 = tid >> 2, kc = (tid & 3) * 16;
    bf16x8 o0, o1;
#pragma unroll
    for (int i = 0; i < 8; ++i) { o0[i] = T[kc + i][e2]; o1[i] = T[kc + 8 + i][e2]; }
    __bf16* dst = out + ((size_t)z << 20) + (size_t)(h * 64 + e2) * 1024 + k0 + kc;
    *(bf16x8*)dst = o0;
    *(bf16x8*)(dst + 8) = o1;
}

__global__ __launch_bounds__(256) void pack_wo(const float* __restrict__ Wo,
                                               __bf16* __restrict__ out) {
    __shared__ __bf16 T[64][72];
    int tid = threadIdx.x;
    int k0 = blockIdx.x * 64, n0 = blockIdx.y * 64;
#pragma unroll
    for (int it = 0; it < 4; ++it) {
        int idx = it * 1024 + tid * 4;
        int r = idx >> 6, e = idx & 63;
        f32x4 val = *(const f32x4*)(Wo + (size_t)(k0 + r) * 1024 + n0 + e);
#pragma unroll
        for (int j = 0; j < 4; ++j) T[r][e + j] = (__bf16)val[j];
    }
    __syncthreads();
    int e2 = tid >> 2, kc = (tid & 3) * 16;
    bf16x8 o0, o1;
#pragma unroll
    for (int i = 0; i < 8; ++i) { o0[i] = T[kc + i][e2]; o1[i] = T[kc + 8 + i][e2]; }
    __bf16* dst = out + (size_t)(n0 + e2) * 1024 + k0 + kc;
    *(bf16x8*)dst = o0;
    *(bf16x8*)(dst + 8) = o1;
}

// vh [B,S,D] bf16 -> vT [B,H,HD,S] bf16
__global__ __launch_bounds__(256) void vtrans(const __bf16* __restrict__ vh,
                                              __bf16* __restrict__ vT) {
    __shared__ __bf16 T[64][72];
    int tid = threadIdx.x;
    int s0 = blockIdx.x * 64, bh = blockIdx.y, b = bh >> 4, h = bh & 15;
#pragma unroll
    for (int it = 0; it < 2; ++it) {
        int idx = it * 2048 + tid * 8;
        int r = idx >> 6, e0 = idx & 63;
        bf16x8 val = *(const bf16x8*)(vh + ((size_t)b * 2048 + s0 + r) * 1024 + h * 64 + e0);
#pragma unroll
        for (int j = 0; j < 8; ++j) T[r][e0 + j] = val[j];
    }
    __syncthreads();
    int e = tid >> 2, sc = (tid & 3) * 16;
    bf16x8 o0, o1;
#pragma unroll
    for (int i = 0; i < 8; ++i) { o0[i] = T[sc + i][e]; o1[i] = T[sc + 8 + i][e]; }
    __bf16* dst = vT + ((size_t)bh * 64 + e) * 2048 + s0 + sc;
    *(bf16x8*)dst = o0;
    *(bf16x8*)(dst + 8) = o1;
}

// ---------------- fused QKV GEMM ----------------
__global__ __launch_bounds__(256) void gemm_qkv(
    const __bf16* __restrict__ qb, const __bf16* __restrict__ kb,
    const __bf16* __restrict__ vb, const __bf16* __restrict__ w3,
    const float* __restrict__ bq, const float* __restrict__ bk,
    const float* __restrict__ bv,
    __bf16* __restrict__ qo, __bf16* __restrict__ ko, __bf16* __restrict__ vo) {
    __shared__ __bf16 As[128 * 64];
    __shared__ __bf16 Bs[128 * 64];
    int z = blockIdx.z;
    const __bf16* A = z == 0 ? qb : (z == 1 ? kb : vb);
    const __bf16* Bt = w3 + ((size_t)z << 20);
    const float* bias = z == 0 ? bq : (z == 1 ? bk : bv);
    __bf16* dst = z == 0 ? qo : (z == 1 ? ko : vo);
    float sc = z == 0 ? QSCL : 1.0f;

    int tid = threadIdx.x;
    int w = tid >> 6, lane = tid & 63, lg = lane >> 4, lr = lane & 15;
    int wr = (w >> 1) * 64, wc = (w & 1) * 64;
    int m0 = blockIdx.y * 128, n0 = blockIdx.x * 128;
    f32x4 acc[4][4] = {};
    for (int k0 = 0; k0 < 1024; k0 += 64) {
        __syncthreads();
        stage_tile<128>(A + (size_t)m0 * 1024 + k0, 1024, As, tid);
        stage_tile<128>(Bt + (size_t)n0 * 1024 + k0, 1024, Bs, tid);
        __syncthreads();
#pragma unroll
        for (int kk = 0; kk < 2; ++kk) {
            bf16x8 af[4], bfr[4];
#pragma unroll
            for (int t = 0; t < 4; ++t) {
                af[t] = lds_frag(As, wr + t * 16 + lr, lg * 16 + kk * 64);
                bfr[t] = lds_frag(Bs, wc + t * 16 + lr, lg * 16 + kk * 64);
            }
#pragma unroll
            for (int i = 0; i < 4; ++i)
#pragma unroll
                for (int j = 0; j < 4; ++j)
                    acc[i][j] = __builtin_amdgcn_mfma_f32_16x16x32_bf16(
                        af[i], bfr[j], acc[i][j], 0, 0, 0);
        }
    }
#pragma unroll
    for (int i = 0; i < 4; ++i) {
        int mb = m0 + wr + i * 16 + lg * 4;
#pragma unroll
        for (int j = 0; j < 4; ++j) {
            int n = n0 + wc + j * 16 + lr;
            float bvv = bias[n];
#pragma unroll
            for (int r = 0; r < 4; ++r)
                dst[(size_t)(mb + r) * 1024 + n] = (__bf16)((acc[i][j][r] + bvv) * sc);
        }
    }
}

// ---------------- final GEMM + GELU (64x128 tile) ----------------
__global__ __launch_bounds__(256) void gemm_out(const __bf16* __restrict__ A,
                                                const __bf16* __restrict__ Bt,
                                                const float* __restrict__ bias,
                                                float* __restrict__ dst) {
    __shared__ __bf16 As[64 * 64];
    __shared__ __bf16 Bs[128 * 64];
    int tid = threadIdx.x;
    int w = tid >> 6, lane = tid & 63, lg = lane >> 4, lr = lane & 15;
    int wr = (w >> 1) * 32, wc = (w & 1) * 64;
    int m0 = blockIdx.y * 64, n0 = blockIdx.x * 128;
    f32x4 acc[2][4] = {};
    for (int k0 = 0; k0 < 1024; k0 += 64) {
        __syncthreads();
        stage_tile<64>(A + (size_t)m0 * 1024 + k0, 1024, As, tid);
        stage_tile<128>(Bt + (size_t)n0 * 1024 + k0, 1024, Bs, tid);
        __syncthreads();
#pragma unroll
        for (int kk = 0; kk < 2; ++kk) {
            bf16x8 af[2], bfr[4];
#pragma unroll
            for (int t = 0; t < 2; ++t)
                af[t] = lds_frag(As, wr + t * 16 + lr, lg * 16 + kk * 64);
#pragma unroll
            for (int t = 0; t < 4; ++t)
                bfr[t] = lds_frag(Bs, wc + t * 16 + lr, lg * 16 + kk * 64);
#pragma unroll
            for (int i = 0; i < 2; ++i)
#pragma unroll
                for (int j = 0; j < 4; ++j)
                    acc[i][j] = __builtin_amdgcn_mfma_f32_16x16x32_bf16(
                        af[i], bfr[j], acc[i][j], 0, 0, 0);
        }
    }
#pragma unroll
    for (int i = 0; i < 2; ++i) {
        int mb = m0 + wr + i * 16 + lg * 4;
#pragma unroll
        for (int j = 0; j < 4; ++j) {
            int n = n0 + wc + j * 16 + lr;
            float bvv = bias[n];
#pragma unroll
            for (int r = 0; r < 4; ++r) {
                float v = acc[i][j][r] + bvv;
                float g = v / (1.f + exp2f(GELC * v));
                dst[(size_t)(mb + r) * 1024 + n] = g;
            }
        }
    }
}

// ---------------- flash attention: in-block kv-split, 8 waves ----------------
// grid (S/128, B*H); 8 waves. grp = w>>2 handles kv half [grp*1024, +1024);
// qsub = w&3 -> 32 q-rows. Each grp has its own dbuf K/V LDS (32KB x 2 grp).
// Max-free log2 softmax => partials additive; combined via LDS at the end.
// Per-tile mask work skipped when flags[(b,q128,kv64)] == 0.
__global__ __launch_bounds__(512, 4) void attn_kernel(
    const __bf16* __restrict__ qs, const __bf16* __restrict__ ks,
    const __bf16* __restrict__ vT, const __bf16* __restrict__ mb0,
    const __bf16* __restrict__ mb1, const unsigned* __restrict__ flags,
    __bf16* __restrict__ x) {
    __shared__ char smem[65536];
    int tid = threadIdx.x;
    int w = tid >> 6, l = tid & 63;
    int grp = w >> 2, qsub = w & 3;
    int gtid = tid & 255;
    int q31 = l & 31, hi = l >> 5;
    int bh = blockIdx.y, b = bh >> 4, h = bh & 15;
    int qt = blockIdx.x;
    int qw = qt * 128 + qsub * 32;
    int kvbase = grp * 1024;

    __bf16* KsL = (__bf16*)(smem + grp * 32768);
    __bf16* VsL = (__bf16*)(smem + grp * 32768 + 16384);

    // Q frags (B-operand): lane holds Q[q=qw+q31][d = kk*16 + hi*8 + j]
    const __bf16* Qp = qs + ((size_t)b * 2048 + qw + q31) * 1024 + h * 64 + hi * 8;
    bf16x8 qf[4];
#pragma unroll
    for (int kk = 0; kk < 4; ++kk) qf[kk] = *(const bf16x8*)(Qp + kk * 16);

    const __bf16* Kb = ks + ((size_t)b * 2048 + kvbase) * 1024 + h * 64;
    const __bf16* Vb = vT + (size_t)bh * 64 * 2048 + kvbase;
    const __bf16* mrow = (b ? mb1 : mb0) + (size_t)(qw + q31) * 2048 + kvbase + hi * 4;
    const unsigned* flg = flags + (b * 16 + qt) * 32 + grp * 16;

    f32x16 O[2] = {};
    float l_acc = 0.f;

    stage_tile<64>(Kb, 1024, KsL, gtid);
    stage_tile<64>(Vb, 2048, VsL, gtid);
    unsigned fl = __builtin_amdgcn_readfirstlane(flg[0]);
    uint2 ml[2][4], mln[2][4];
    if (fl) {
#pragma unroll
        for (int mt = 0; mt < 2; ++mt)
#pragma unroll
            for (int g = 0; g < 4; ++g)
                ml[mt][g] = *(const uint2*)(mrow + mt * 32 + g * 8);
    }

    for (int kt = 0; kt < 16; ++kt) {
        int buf = kt & 1;
        __syncthreads();   // buf staged (barrier drains vmcnt); buf^1 free
        unsigned nfl = 0;
        if (kt < 15) {
            stage_tile<64>(Kb + (size_t)(kt + 1) * 64 * 1024, 1024, KsL + (buf ^ 1) * 4096, gtid);
            stage_tile<64>(Vb + (kt + 1) * 64, 2048, VsL + (buf ^ 1) * 4096, gtid);
            nfl = __builtin_amdgcn_readfirstlane(flg[kt + 1]);
            if (nfl) {
#pragma unroll
                for (int mt = 0; mt < 2; ++mt)
#pragma unroll
                    for (int g = 0; g < 4; ++g)
                        mln[mt][g] = *(const uint2*)(mrow + (kt + 1) * 64 + mt * 32 + g * 8);
            }
        }
        // frags from LDS
        bf16x8 kf[2][4], vf[2][4];
#pragma unroll
        for (int mt = 0; mt < 2; ++mt)
#pragma unroll
            for (int kk = 0; kk < 4; ++kk) {
                kf[mt][kk] = lds_frag(KsL + buf * 4096, mt * 32 + q31, kk * 32 + hi * 16);
                vf[mt][kk] = lds_frag(VsL + buf * 4096, mt * 32 + q31, kk * 32 + hi * 16);
            }
        f32x16 T[2] = {};
        __builtin_amdgcn_s_setprio(1);
#pragma unroll
        for (int kk = 0; kk < 4; ++kk)
#pragma unroll
            for (int mt = 0; mt < 2; ++mt)
                T[mt] = __builtin_amdgcn_mfma_f32_32x32x16_bf16(kf[mt][kk], qf[kk], T[mt], 0, 0, 0);
        __builtin_amdgcn_s_setprio(0);

        // softmax (max-free, log2 domain)
        if (fl) {
#pragma unroll
            for (int mt = 0; mt < 2; ++mt)
#pragma unroll
                for (int g = 0; g < 4; ++g) {
                    float f0 = __uint_as_float(ml[mt][g].x << 16);
                    float f1 = __uint_as_float(ml[mt][g].x & 0xffff0000u);
                    float f2 = __uint_as_float(ml[mt][g].y << 16);
                    float f3 = __uint_as_float(ml[mt][g].y & 0xffff0000u);
                    float p0 = exp2f(T[mt][4 * g + 0] + f0);
                    float p1 = exp2f(T[mt][4 * g + 1] + f1);
                    float p2 = exp2f(T[mt][4 * g + 2] + f2);
                    float p3 = exp2f(T[mt][4 * g + 3] + f3);
                    l_acc += (p0 + p1) + (p2 + p3);
                    T[mt][4 * g + 0] = p0; T[mt][4 * g + 1] = p1;
                    T[mt][4 * g + 2] = p2; T[mt][4 * g + 3] = p3;
                }
        } else {
#pragma unroll
            for (int mt = 0; mt < 2; ++mt)
#pragma unroll
                for (int g = 0; g < 4; ++g) {
                    float p0 = exp2f(T[mt][4 * g + 0]);
                    float p1 = exp2f(T[mt][4 * g + 1]);
                    float p2 = exp2f(T[mt][4 * g + 2]);
                    float p3 = exp2f(T[mt][4 * g + 3]);
                    l_acc += (p0 + p1) + (p2 + p3);
                    T[mt][4 * g + 0] = p0; T[mt][4 * g + 1] = p1;
                    T[mt][4 * g + 2] = p2; T[mt][4 * g + 3] = p3;
                }
        }
#pragma unroll
        for (int mt = 0; mt < 2; ++mt)
#pragma unroll
            for (int g = 0; g < 4; ++g) ml[mt][g] = mln[mt][g];
        fl = nfl;

        // P frags in-register: pf[kk][j] = P[q=q31][kv = kk*16 + hi*8 + j]
        bf16x8 pf[4];
#pragma unroll
        for (int kk = 0; kk < 4; ++kk) {
            int mt = kk >> 1;
            int gA = (2 * kk) & 3, gB = gA + 1;
            unsigned x0 = cvtpk(T[mt][4 * gA + 0], T[mt][4 * gA + 1]);
            unsigned x1 = cvtpk(T[mt][4 * gA + 2], T[mt][4 * gA + 3]);
            unsigned y0 = cvtpk(T[mt][4 * gB + 0], T[mt][4 * gB + 1]);
            unsigned y1 = cvtpk(T[mt][4 * gB + 2], T[mt][4 * gB + 3]);
            pswap(x0, y0);
            pswap(x1, y1);
            u32x4 packed; packed[0] = x0; packed[1] = x1; packed[2] = y0; packed[3] = y1;
            pf[kk] = __builtin_bit_cast(bf16x8, packed);
        }

        __builtin_amdgcn_s_setprio(1);
#pragma unroll
        for (int kk = 0; kk < 4; ++kk)
#pragma unroll
            for (int mt = 0; mt < 2; ++mt)
                O[mt] = __builtin_amdgcn_mfma_f32_32x32x16_bf16(vf[mt][kk], pf[kk], O[mt], 0, 0, 0);
        __builtin_amdgcn_s_setprio(0);
    }

    // combine the two kv-half partials through LDS (additive: max-free)
    __syncthreads();
    float* sx = (float*)smem;
    if (grp == 1) {
        float* p = sx + (size_t)qsub * 2112 + l * 33;
#pragma unroll
        for (int mt = 0; mt < 2; ++mt)
#pragma unroll
            for (int i = 0; i < 16; ++i) p[mt * 16 + i] = O[mt][i];
        p[32] = l_acc;
    }
    __syncthreads();
    if (grp == 0) {
        float* p = sx + (size_t)qsub * 2112 + l * 33;
#pragma unroll
        for (int mt = 0; mt < 2; ++mt)
#pragma unroll
            for (int i = 0; i < 16; ++i) O[mt][i] += p[mt * 16 + i];
        l_acc += p[32];
        l_acc += __shfl_xor(l_acc, 32, 64);
        float inv = 1.0f / l_acc;
        // O[mt][r]: e = mt*32 + (r&3) + 8*(r>>2) + 4*hi, q = q31
        __bf16* xp = x + ((size_t)b * 2048 + qw + q31) * 1024 + h * 64 + hi * 4;
#pragma unroll
        for (int mt = 0; mt < 2; ++mt)
#pragma unroll
            for (int g = 0; g < 4; ++g) {
                bf16x4 o;
#pragma unroll
                for (int c = 0; c < 4; ++c) o[c] = (__bf16)(O[mt][4 * g + c] * inv);
                *(bf16x4*)(xp + mt * 32 + g * 8) = o;
            }
    }
}

// ---------------- launch ----------------

extern "C" void kernel_launch(void* const* d_in, const int* in_sizes, int n_in,
                              void* d_out, int out_size, void* d_ws, size_t ws_size,
                              hipStream_t stream) {
    const float* q    = (const float*)d_in[0];
    const float* k    = (const float*)d_in[1];
    const float* v    = (const float*)d_in[2];
    const float* mask = (const float*)d_in[3];
    const float* Wq   = (const float*)d_in[4];
    const float* bq   = (const float*)d_in[5];
    const float* Wk   = (const float*)d_in[6];
    const float* bk   = (const float*)d_in[7];
    const float* Wv   = (const float*)d_in[8];
    const float* bv   = (const float*)d_in[9];
    const float* Wo   = (const float*)d_in[10];
    const float* bo   = (const float*)d_in[11];

    char* ws = (char*)d_ws;
    __bf16* qb  = (__bf16*)(ws + (0ull  << 20));   // reused as vT
    __bf16* kb  = (__bf16*)(ws + (8ull  << 20));   // reused as x
    __bf16* vb  = (__bf16*)(ws + (16ull << 20));   // reused as mb0
    __bf16* w3  = (__bf16*)(ws + (24ull << 20));   // 6 MB
    __bf16* wo  = (__bf16*)(ws + (30ull << 20));   // 2 MB
    __bf16* qhp = (__bf16*)(ws + (32ull << 20));
    __bf16* khp = (__bf16*)(ws + (40ull << 20));
    __bf16* vhp = (__bf16*)(ws + (48ull << 20));   // reused as mb1
    unsigned* flagp = (unsigned*)(ws + (56ull << 20));  // 4 KB
    __bf16* vTp = qb;
    __bf16* xp  = kb;
    __bf16* mb0p = vb;
    __bf16* mb1p = vhp;

    cvt3_kernel<<<dim3(4096, 3), 256, 0, stream>>>(q, k, v, qb, kb, vb);
    pack_wqkv<<<dim3(16, 16, 3), 256, 0, stream>>>(Wq, Wk, Wv, w3);
    pack_wo<<<dim3(16, 16), 256, 0, stream>>>(Wo, wo);

    gemm_qkv<<<dim3(8, 32, 3), 256, 0, stream>>>(qb, kb, vb, w3, bq, bk, bv,
                                                 qhp, khp, vhp);
    vtrans<<<dim3(32, 32), 256, 0, stream>>>(vhp, vTp);
    flags_init<<<1, 256, 0, stream>>>(flagp);
    mask_prep<<<dim3(4096, 2), 256, 0, stream>>>(mask, mb0p, mb1p, flagp);

    attn_kernel<<<dim3(16, 32), 512, 0, stream>>>(qhp, khp, vTp, mb0p, mb1p,
                                                  flagp, xp);

    gemm_out<<<dim3(8, 64), 256, 0, stream>>>(xp, wo, bo, (float*)d_out);
}

// Round 7
// 354.512 us; speedup vs baseline: 1.0982x; 1.0982x over previous
//
#include <hip/hip_runtime.h>
#include <stdint.h>

// MultiHeadedAttention: B=2,S=2048,D=1024,H=16,HD=64
// R7: attn kv-split ACROSS BLOCKS (grid z=2, 16 tiles each; 1024 blocks ->
// 4 blocks/CU = 16 waves/CU). Max-free partials are additive: f32 atomicAdd
// into zeroed Oacc/lacc (exactly 2 addends/address => deterministic), then a
// normalize kernel emits bf16 x. Mask: per-tile nonzero flags gate direct f32
// loads (zero mask => zero traffic); bf16 mask prep dropped. Kernel internals
// otherwise = R5 (256-thr, 32x32x16 MFMA, in-reg P, LDS dbuf K/V). NO
// restrictive launch_bounds (R6 lesson: cap => spill => 554MB scratch).
// Workspace (MB): 0-8 qb/x, 8-16 kb/vT, 16-24 vb/Oacc0, 24-30 w3, 30-32 wo,
// 32-40 qh, 40-48 kh, 48-56 vh/Oacc1, 56-56.25 lacc, +4KB flags

typedef __bf16 bf16x8 __attribute__((ext_vector_type(8)));
typedef __bf16 bf16x4 __attribute__((ext_vector_type(4)));
typedef float f32x4 __attribute__((ext_vector_type(4)));
typedef float f32x16 __attribute__((ext_vector_type(16)));
typedef unsigned u32x4 __attribute__((ext_vector_type(4)));

static constexpr float L2E  = 1.4426950408889634f;
static constexpr float QSCL = 0.18033688011112042f;   // 0.125 * log2(e)
static constexpr float GELC = -2.4554669595930157f;   // -1.702 * log2(e)

__device__ __forceinline__ void async_load16(const void* g, void* l) {
    __builtin_amdgcn_global_load_lds(
        (const __attribute__((address_space(1))) unsigned int*)(uintptr_t)g,
        (__attribute__((address_space(3))) unsigned int*)(unsigned int)(uintptr_t)l,
        16, 0, 0);
}

// Stage ROWS x 64-bf16 tile into LDS, phys = row*128 + (kb ^ ((row&7)<<4)).
template <int ROWS>
__device__ __forceinline__ void stage_tile(const __bf16* g, int ld, __bf16* lds, int tid) {
#pragma unroll
    for (int r = 0; r < ROWS / 32; ++r) {
        int p = r * 4096 + tid * 16;
        int row = p >> 7;
        int kbp = p & 127;
        int kbl = kbp ^ ((row & 7) << 4);
        async_load16((const char*)(g + (size_t)row * ld) + kbl,
                     (char*)lds + (p & ~1023));
    }
}

__device__ __forceinline__ bf16x8 lds_frag(const __bf16* base, int row, int kb) {
    return *(const bf16x8*)((const char*)base + (row << 7) + (kb ^ ((row & 7) << 4)));
}

__device__ __forceinline__ unsigned cvtpk(float a, float b) {
    unsigned d;
    asm("v_cvt_pk_bf16_f32 %0, %1, %2" : "=v"(d) : "v"(a), "v"(b));
    return d;
}
__device__ __forceinline__ void pswap(unsigned& a, unsigned& b) {
    asm("v_permlane32_swap_b32 %0, %1" : "+v"(a), "+v"(b));
}

// ---------------- prep kernels ----------------

__global__ __launch_bounds__(256) void cvt3_kernel(const float* __restrict__ q,
                                                   const float* __restrict__ k,
                                                   const float* __restrict__ v,
                                                   __bf16* __restrict__ qb,
                                                   __bf16* __restrict__ kb,
                                                   __bf16* __restrict__ vb) {
    int z = blockIdx.y;
    const float* src = z == 0 ? q : (z == 1 ? k : v);
    __bf16* dst = z == 0 ? qb : (z == 1 ? kb : vb);
    int i = blockIdx.x * 256 + threadIdx.x;
    f32x4 val = ((const f32x4*)src)[i];
    bf16x4 o;
    o[0] = (__bf16)val[0]; o[1] = (__bf16)val[1];
    o[2] = (__bf16)val[2]; o[3] = (__bf16)val[3];
    ((bf16x4*)dst)[i] = o;
}

__global__ __launch_bounds__(256) void flags_init(unsigned* __restrict__ flags) {
    int t = threadIdx.x;
#pragma unroll
    for (int k = 0; k < 4; ++k) flags[t + k * 256] = 0u;
}

// Per-(b, q/128, kv/64) nonzero flags from the f32 mask (zero mask => 0 atomics)
__global__ __launch_bounds__(256) void mask_flags(const float* __restrict__ m,
                                                  unsigned* __restrict__ flags) {
    int i = blockIdx.x * 256 + threadIdx.x;    // over B*S*S/4 = 2,097,152
    f32x4 v = ((const f32x4*)m)[i];
    bool nz = (v[0] != 0.f) | (v[1] != 0.f) | (v[2] != 0.f) | (v[3] != 0.f);
    if (nz) {
        size_t i4 = (size_t)i * 4;
        int b = (int)(i4 >> 22);
        int rem = (int)(i4 & 4194303);
        int qq = rem >> 11, kv = rem & 2047;
        atomicOr(flags + (b * 16 + (qq >> 7)) * 32 + (kv >> 6), 1u);
    }
}

__global__ __launch_bounds__(256) void pack_wqkv(const float* __restrict__ Wq,
                                                 const float* __restrict__ Wk,
                                                 const float* __restrict__ Wv,
                                                 __bf16* __restrict__ out) {
    __shared__ __bf16 T[64][72];
    int tid = threadIdx.x;
    int k0 = blockIdx.x * 64, h = blockIdx.y, z = blockIdx.z;
    const float* W = z == 0 ? Wq : (z == 1 ? Wk : Wv);
#pragma unroll
    for (int it = 0; it < 4; ++it) {
        int idx = it * 1024 + tid * 4;
        int r = idx >> 6, e = idx & 63;
        f32x4 val = *(const f32x4*)(W + ((size_t)h * 1024 + k0 + r) * 64 + e);
#pragma unroll
        for (int j = 0; j < 4; ++j) T[r][e + j] = (__bf16)val[j];
    }
    __syncthreads();
    int e2 = tid >> 2, kc = (tid & 3) * 16;
    bf16x8 o0, o1;
#pragma unroll
    for (int i = 0; i < 8; ++i) { o0[i] = T[kc + i][e2]; o1[i] = T[kc + 8 + i][e2]; }
    __bf16* dst = out + ((size_t)z << 20) + (size_t)(h * 64 + e2) * 1024 + k0 + kc;
    *(bf16x8*)dst = o0;
    *(bf16x8*)(dst + 8) = o1;
}

__global__ __launch_bounds__(256) void pack_wo(const float* __restrict__ Wo,
                                               __bf16* __restrict__ out) {
    __shared__ __bf16 T[64][72];
    int tid = threadIdx.x;
    int k0 = blockIdx.x * 64, n0 = blockIdx.y * 64;
#pragma unroll
    for (int it = 0; it < 4; ++it) {
        int idx = it * 1024 + tid * 4;
        int r = idx >> 6, e = idx & 63;
        f32x4 val = *(const f32x4*)(Wo + (size_t)(k0 + r) * 1024 + n0 + e);
#pragma unroll
        for (int j = 0; j < 4; ++j) T[r][e + j] = (__bf16)val[j];
    }
    __syncthreads();
    int e2 = tid >> 2, kc = (tid & 3) * 16;
    bf16x8 o0, o1;
#pragma unroll
    for (int i = 0; i < 8; ++i) { o0[i] = T[kc + i][e2]; o1[i] = T[kc + 8 + i][e2]; }
    __bf16* dst = out + (size_t)(n0 + e2) * 1024 + k0 + kc;
    *(bf16x8*)dst = o0;
    *(bf16x8*)(dst + 8) = o1;
}

// vh [B,S,D] bf16 -> vT [B,H,HD,S] bf16
__global__ __launch_bounds__(256) void vtrans(const __bf16* __restrict__ vh,
                                              __bf16* __restrict__ vT) {
    __shared__ __bf16 T[64][72];
    int tid = threadIdx.x;
    int s0 = blockIdx.x * 64, bh = blockIdx.y, b = bh >> 4, h = bh & 15;
#pragma unroll
    for (int it = 0; it < 2; ++it) {
        int idx = it * 2048 + tid * 8;
        int r = idx >> 6, e0 = idx & 63;
        bf16x8 val = *(const bf16x8*)(vh + ((size_t)b * 2048 + s0 + r) * 1024 + h * 64 + e0);
#pragma unroll
        for (int j = 0; j < 8; ++j) T[r][e0 + j] = val[j];
    }
    __syncthreads();
    int e = tid >> 2, sc = (tid & 3) * 16;
    bf16x8 o0, o1;
#pragma unroll
    for (int i = 0; i < 8; ++i) { o0[i] = T[sc + i][e]; o1[i] = T[sc + 8 + i][e]; }
    __bf16* dst = vT + ((size_t)bh * 64 + e) * 2048 + s0 + sc;
    *(bf16x8*)dst = o0;
    *(bf16x8*)(dst + 8) = o1;
}

// ---------------- fused QKV GEMM ----------------
__global__ __launch_bounds__(256) void gemm_qkv(
    const __bf16* __restrict__ qb, const __bf16* __restrict__ kb,
    const __bf16* __restrict__ vb, const __bf16* __restrict__ w3,
    const float* __restrict__ bq, const float* __restrict__ bk,
    const float* __restrict__ bv,
    __bf16* __restrict__ qo, __bf16* __restrict__ ko, __bf16* __restrict__ vo) {
    __shared__ __bf16 As[128 * 64];
    __shared__ __bf16 Bs[128 * 64];
    int z = blockIdx.z;
    const __bf16* A = z == 0 ? qb : (z == 1 ? kb : vb);
    const __bf16* Bt = w3 + ((size_t)z << 20);
    const float* bias = z == 0 ? bq : (z == 1 ? bk : bv);
    __bf16* dst = z == 0 ? qo : (z == 1 ? ko : vo);
    float sc = z == 0 ? QSCL : 1.0f;

    int tid = threadIdx.x;
    int w = tid >> 6, lane = tid & 63, lg = lane >> 4, lr = lane & 15;
    int wr = (w >> 1) * 64, wc = (w & 1) * 64;
    int m0 = blockIdx.y * 128, n0 = blockIdx.x * 128;
    f32x4 acc[4][4] = {};
    for (int k0 = 0; k0 < 1024; k0 += 64) {
        __syncthreads();
        stage_tile<128>(A + (size_t)m0 * 1024 + k0, 1024, As, tid);
        stage_tile<128>(Bt + (size_t)n0 * 1024 + k0, 1024, Bs, tid);
        __syncthreads();
#pragma unroll
        for (int kk = 0; kk < 2; ++kk) {
            bf16x8 af[4], bfr[4];
#pragma unroll
            for (int t = 0; t < 4; ++t) {
                af[t] = lds_frag(As, wr + t * 16 + lr, lg * 16 + kk * 64);
                bfr[t] = lds_frag(Bs, wc + t * 16 + lr, lg * 16 + kk * 64);
            }
#pragma unroll
            for (int i = 0; i < 4; ++i)
#pragma unroll
                for (int j = 0; j < 4; ++j)
                    acc[i][j] = __builtin_amdgcn_mfma_f32_16x16x32_bf16(
                        af[i], bfr[j], acc[i][j], 0, 0, 0);
        }
    }
#pragma unroll
    for (int i = 0; i < 4; ++i) {
        int mb = m0 + wr + i * 16 + lg * 4;
#pragma unroll
        for (int j = 0; j < 4; ++j) {
            int n = n0 + wc + j * 16 + lr;
            float bvv = bias[n];
#pragma unroll
            for (int r = 0; r < 4; ++r)
                dst[(size_t)(mb + r) * 1024 + n] = (__bf16)((acc[i][j][r] + bvv) * sc);
        }
    }
}

// ---------------- final GEMM + GELU (64x128 tile) ----------------
__global__ __launch_bounds__(256) void gemm_out(const __bf16* __restrict__ A,
                                                const __bf16* __restrict__ Bt,
                                                const float* __restrict__ bias,
                                                float* __restrict__ dst) {
    __shared__ __bf16 As[64 * 64];
    __shared__ __bf16 Bs[128 * 64];
    int tid = threadIdx.x;
    int w = tid >> 6, lane = tid & 63, lg = lane >> 4, lr = lane & 15;
    int wr = (w >> 1) * 32, wc = (w & 1) * 64;
    int m0 = blockIdx.y * 64, n0 = blockIdx.x * 128;
    f32x4 acc[2][4] = {};
    for (int k0 = 0; k0 < 1024; k0 += 64) {
        __syncthreads();
        stage_tile<64>(A + (size_t)m0 * 1024 + k0, 1024, As, tid);
        stage_tile<128>(Bt + (size_t)n0 * 1024 + k0, 1024, Bs, tid);
        __syncthreads();
#pragma unroll
        for (int kk = 0; kk < 2; ++kk) {
            bf16x8 af[2], bfr[4];
#pragma unroll
            for (int t = 0; t < 2; ++t)
                af[t] = lds_frag(As, wr + t * 16 + lr, lg * 16 + kk * 64);
#pragma unroll
            for (int t = 0; t < 4; ++t)
                bfr[t] = lds_frag(Bs, wc + t * 16 + lr, lg * 16 + kk * 64);
#pragma unroll
            for (int i = 0; i < 2; ++i)
#pragma unroll
                for (int j = 0; j < 4; ++j)
                    acc[i][j] = __builtin_amdgcn_mfma_f32_16x16x32_bf16(
                        af[i], bfr[j], acc[i][j], 0, 0, 0);
        }
    }
#pragma unroll
    for (int i = 0; i < 2; ++i) {
        int mb = m0 + wr + i * 16 + lg * 4;
#pragma unroll
        for (int j = 0; j < 4; ++j) {
            int n = n0 + wc + j * 16 + lr;
            float bvv = bias[n];
#pragma unroll
            for (int r = 0; r < 4; ++r) {
                float v = acc[i][j][r] + bvv;
                float g = v / (1.f + exp2f(GELC * v));
                dst[(size_t)(mb + r) * 1024 + n] = g;
            }
        }
    }
}

// ---------------- flash attention: block-level kv-split ----------------
// grid (S/128, B*H, 2); 4 waves x 32 q-rows. Block z sweeps kv [z*1024,+1024)
// in 16 64-tiles (LDS dbuf K/V). Max-free log2 softmax => partials additive;
// f32 atomicAdd into Oacc/lacc (2 addends/address -> deterministic).
// Mask: flag-gated direct f32 loads (zero traffic for zero mask).
__global__ __launch_bounds__(256) void attn_kernel(
    const __bf16* __restrict__ qs, const __bf16* __restrict__ ks,
    const __bf16* __restrict__ vT, const float* __restrict__ mask,
    const unsigned* __restrict__ flags,
    float* __restrict__ Oacc0, float* __restrict__ Oacc1,
    float* __restrict__ lacc) {
    __shared__ __bf16 Ks[2][64 * 64];
    __shared__ __bf16 Vs[2][64 * 64];
    int tid = threadIdx.x;
    int w = tid >> 6, l = tid & 63;
    int q31 = l & 31, hi = l >> 5;
    int bh = blockIdx.y, b = bh >> 4, h = bh & 15;
    int qt = blockIdx.x;
    int qw = qt * 128 + w * 32;
    int z = blockIdx.z, kvbase = z << 10;

    // Q frags (B-operand): lane holds Q[q=qw+q31][d = kk*16 + hi*8 + j]
    const __bf16* Qp = qs + ((size_t)b * 2048 + qw + q31) * 1024 + h * 64 + hi * 8;
    bf16x8 qf[4];
#pragma unroll
    for (int kk = 0; kk < 4; ++kk) qf[kk] = *(const bf16x8*)(Qp + kk * 16);

    const __bf16* Kb = ks + ((size_t)b * 2048 + kvbase) * 1024 + h * 64;
    const __bf16* Vb = vT + (size_t)bh * 64 * 2048 + kvbase;
    const float* mrow = mask + (size_t)b * 4194304 + (size_t)(qw + q31) * 2048 + kvbase + hi * 4;
    const unsigned* flg = flags + (b * 16 + qt) * 32 + z * 16;

    f32x16 O[2] = {};
    float l_acc = 0.f;

    stage_tile<64>(Kb, 1024, Ks[0], tid);
    stage_tile<64>(Vb, 2048, Vs[0], tid);

    for (int kt = 0; kt < 16; ++kt) {
        int buf = kt & 1;
        __syncthreads();   // buf staged (barrier drains vmcnt); buf^1 free
        if (kt < 15) {
            stage_tile<64>(Kb + (size_t)(kt + 1) * 64 * 1024, 1024, Ks[buf ^ 1], tid);
            stage_tile<64>(Vb + (kt + 1) * 64, 2048, Vs[buf ^ 1], tid);
        }
        // K frags from LDS: A[kv = mt*32 + q31][d = kk*16 + hi*8 ..+8]
        bf16x8 kf[2][4];
#pragma unroll
        for (int mt = 0; mt < 2; ++mt)
#pragma unroll
            for (int kk = 0; kk < 4; ++kk)
                kf[mt][kk] = lds_frag(Ks[buf], mt * 32 + q31, kk * 32 + hi * 16);
        f32x16 T[2] = {};
        __builtin_amdgcn_s_setprio(1);
#pragma unroll
        for (int kk = 0; kk < 4; ++kk)
#pragma unroll
            for (int mt = 0; mt < 2; ++mt)
                T[mt] = __builtin_amdgcn_mfma_f32_32x32x16_bf16(kf[mt][kk], qf[kk], T[mt], 0, 0, 0);
        __builtin_amdgcn_s_setprio(0);

        // flag-gated mask add (wave-uniform branch), then max-free exp2
        unsigned fl = __builtin_amdgcn_readfirstlane(flg[kt]);
        if (fl) {
#pragma unroll
            for (int mt = 0; mt < 2; ++mt)
#pragma unroll
                for (int g = 0; g < 4; ++g) {
                    f32x4 mk = *(const f32x4*)(mrow + kt * 64 + mt * 32 + g * 8);
#pragma unroll
                    for (int c = 0; c < 4; ++c)
                        T[mt][4 * g + c] = fmaf(mk[c], L2E, T[mt][4 * g + c]);
                }
        }
#pragma unroll
        for (int mt = 0; mt < 2; ++mt)
#pragma unroll
            for (int g = 0; g < 4; ++g) {
                float p0 = exp2f(T[mt][4 * g + 0]);
                float p1 = exp2f(T[mt][4 * g + 1]);
                float p2 = exp2f(T[mt][4 * g + 2]);
                float p3 = exp2f(T[mt][4 * g + 3]);
                l_acc += (p0 + p1) + (p2 + p3);
                T[mt][4 * g + 0] = p0; T[mt][4 * g + 1] = p1;
                T[mt][4 * g + 2] = p2; T[mt][4 * g + 3] = p3;
            }

        // P frags in-register: pf[kk][j] = P[q=q31][kv = kk*16 + hi*8 + j]
        bf16x8 pf[4];
#pragma unroll
        for (int kk = 0; kk < 4; ++kk) {
            int mt = kk >> 1;
            int gA = (2 * kk) & 3, gB = gA + 1;
            unsigned x0 = cvtpk(T[mt][4 * gA + 0], T[mt][4 * gA + 1]);
            unsigned x1 = cvtpk(T[mt][4 * gA + 2], T[mt][4 * gA + 3]);
            unsigned y0 = cvtpk(T[mt][4 * gB + 0], T[mt][4 * gB + 1]);
            unsigned y1 = cvtpk(T[mt][4 * gB + 2], T[mt][4 * gB + 3]);
            pswap(x0, y0);
            pswap(x1, y1);
            u32x4 packed; packed[0] = x0; packed[1] = x1; packed[2] = y0; packed[3] = y1;
            pf[kk] = __builtin_bit_cast(bf16x8, packed);
        }

        // V frags read late (lower peak VGPR)
        bf16x8 vf[2][4];
#pragma unroll
        for (int mt = 0; mt < 2; ++mt)
#pragma unroll
            for (int kk = 0; kk < 4; ++kk)
                vf[mt][kk] = lds_frag(Vs[buf], mt * 32 + q31, kk * 32 + hi * 16);

        __builtin_amdgcn_s_setprio(1);
#pragma unroll
        for (int kk = 0; kk < 4; ++kk)
#pragma unroll
            for (int mt = 0; mt < 2; ++mt)
                O[mt] = __builtin_amdgcn_mfma_f32_32x32x16_bf16(vf[mt][kk], pf[kk], O[mt], 0, 0, 0);
        __builtin_amdgcn_s_setprio(0);
    }

    // additive combine: f32 atomics (exactly 2 contributions per address)
    l_acc += __shfl_xor(l_acc, 32, 64);
    if (hi == 0)
        atomicAdd(lacc + ((size_t)(b * 16 + h)) * 2048 + qw + q31, l_acc);
    float* Ob = (b ? Oacc1 : Oacc0) + ((size_t)h * 2048 + qw + q31) * 64 + hi * 4;
#pragma unroll
    for (int mt = 0; mt < 2; ++mt)
#pragma unroll
        for (int g = 0; g < 4; ++g)
#pragma unroll
            for (int c = 0; c < 4; ++c)
                atomicAdd(Ob + mt * 32 + g * 8 + c, O[mt][4 * g + c]);
}

// normalize: x[b,s,h*64+e] = bf16(Oacc[b][h][s][e] / lacc[b][h][s])
__global__ __launch_bounds__(256) void attn_norm(const float* __restrict__ Oacc0,
                                                 const float* __restrict__ Oacc1,
                                                 const float* __restrict__ lacc,
                                                 __bf16* __restrict__ x) {
    int idx = blockIdx.x * 256 + threadIdx.x;   // 1,048,576 total
    int b = idx >> 19;
    int rem = idx & 524287;                     // h[4] s[11] e4[4]
    int h = rem >> 15;
    int s = (rem >> 4) & 2047;
    int e0 = (rem & 15) * 4;
    const float* Ob = b ? Oacc1 : Oacc0;
    f32x4 o = *(const f32x4*)(Ob + ((size_t)h * 2048 + s) * 64 + e0);
    float inv = 1.0f / lacc[((size_t)(b * 16 + h)) * 2048 + s];
    bf16x4 r;
#pragma unroll
    for (int c = 0; c < 4; ++c) r[c] = (__bf16)(o[c] * inv);
    *(bf16x4*)(x + ((size_t)b * 2048 + s) * 1024 + h * 64 + e0) = r;
}

// ---------------- launch ----------------

extern "C" void kernel_launch(void* const* d_in, const int* in_sizes, int n_in,
                              void* d_out, int out_size, void* d_ws, size_t ws_size,
                              hipStream_t stream) {
    const float* q    = (const float*)d_in[0];
    const float* k    = (const float*)d_in[1];
    const float* v    = (const float*)d_in[2];
    const float* mask = (const float*)d_in[3];
    const float* Wq   = (const float*)d_in[4];
    const float* bq   = (const float*)d_in[5];
    const float* Wk   = (const float*)d_in[6];
    const float* bk   = (const float*)d_in[7];
    const float* Wv   = (const float*)d_in[8];
    const float* bv   = (const float*)d_in[9];
    const float* Wo   = (const float*)d_in[10];
    const float* bo   = (const float*)d_in[11];

    char* ws = (char*)d_ws;
    __bf16* qb  = (__bf16*)(ws + (0ull  << 20));   // reused as x
    __bf16* kb  = (__bf16*)(ws + (8ull  << 20));   // reused as vT
    __bf16* vb  = (__bf16*)(ws + (16ull << 20));   // reused as Oacc0 (8MB f32)
    __bf16* w3  = (__bf16*)(ws + (24ull << 20));   // 6 MB
    __bf16* wo  = (__bf16*)(ws + (30ull << 20));   // 2 MB
    __bf16* qhp = (__bf16*)(ws + (32ull << 20));
    __bf16* khp = (__bf16*)(ws + (40ull << 20));
    __bf16* vhp = (__bf16*)(ws + (48ull << 20));   // reused as Oacc1 (8MB f32)
    float*  laccp = (float*)(ws + (56ull << 20));                 // 256 KB
    unsigned* flagp = (unsigned*)(ws + (56ull << 20) + (256ull << 10));  // 4 KB
    __bf16* xp   = qb;
    __bf16* vTp  = kb;
    float*  Oa0  = (float*)vb;
    float*  Oa1  = (float*)vhp;

    cvt3_kernel<<<dim3(4096, 3), 256, 0, stream>>>(q, k, v, qb, kb, vb);
    pack_wqkv<<<dim3(16, 16, 3), 256, 0, stream>>>(Wq, Wk, Wv, w3);
    pack_wo<<<dim3(16, 16), 256, 0, stream>>>(Wo, wo);
    flags_init<<<1, 256, 0, stream>>>(flagp);
    mask_flags<<<8192, 256, 0, stream>>>(mask, flagp);

    gemm_qkv<<<dim3(8, 32, 3), 256, 0, stream>>>(qb, kb, vb, w3, bq, bk, bv,
                                                 qhp, khp, vhp);
    vtrans<<<dim3(32, 32), 256, 0, stream>>>(vhp, vTp);

    hipMemsetAsync(Oa0, 0, 8ull << 20, stream);
    hipMemsetAsync(Oa1, 0, 8ull << 20, stream);
    hipMemsetAsync(laccp, 0, 256ull << 10, stream);

    attn_kernel<<<dim3(16, 32, 2), 256, 0, stream>>>(qhp, khp, vTp, mask, flagp,
                                                     Oa0, Oa1, laccp);
    attn_norm<<<4096, 256, 0, stream>>>(Oa0, Oa1, laccp, xp);

    gemm_out<<<dim3(8, 64), 256, 0, stream>>>(xp, wo, bo, (float*)d_out);
}

// Round 8
// 170.753 us; speedup vs baseline: 2.2800x; 2.0762x over previous
//
#include <hip/hip_runtime.h>
#include <stdint.h>

// MultiHeadedAttention: B=2,S=2048,D=1024,H=16,HD=64
// R8: attn kv-split across blocks (grid z=2 -> 1024 blocks, 4/CU, 16 waves/CU)
// with CHEAP combine: coalesced bf16 partial-O stores + plain f32 partial-l
// stores (exactly one writer per address -> no atomics, no memsets; R7's
// atomicAdd caused 16x write amplification = 158us). attn_norm adds halves in
// f32, normalizes, writes bf16 x. Inner loop = R5/R7 (LDS dbuf K/V, 32x32x16
// MFMA, in-reg P via cvt_pk+permlane32_swap, flag-gated f32 mask, max-free
// log2 softmax).
// Workspace map (MB):
//   0-8   qb   -> vT (after gemm_qkv)
//   8-16  kb   -> Opart z=0 (bf16 [B][H][S][64])
//   16-24 vb   -> Opart z=1
//   24-30 w3
//   30-32 wo                  (live until gemm_out)
//   32-40 qh
//   40-48 kh
//   48-56 vh   -> x (bf16, written by attn_norm)
//   56-56.5    lacc (f32 [2][32][2048])
//   56.5+      flags (4KB)

typedef __bf16 bf16x8 __attribute__((ext_vector_type(8)));
typedef __bf16 bf16x4 __attribute__((ext_vector_type(4)));
typedef float f32x4 __attribute__((ext_vector_type(4)));
typedef float f32x16 __attribute__((ext_vector_type(16)));
typedef unsigned u32x4 __attribute__((ext_vector_type(4)));

static constexpr float L2E  = 1.4426950408889634f;
static constexpr float QSCL = 0.18033688011112042f;   // 0.125 * log2(e)
static constexpr float GELC = -2.4554669595930157f;   // -1.702 * log2(e)

__device__ __forceinline__ void async_load16(const void* g, void* l) {
    __builtin_amdgcn_global_load_lds(
        (const __attribute__((address_space(1))) unsigned int*)(uintptr_t)g,
        (__attribute__((address_space(3))) unsigned int*)(unsigned int)(uintptr_t)l,
        16, 0, 0);
}

// Stage ROWS x 64-bf16 tile into LDS, phys = row*128 + (kb ^ ((row&7)<<4)).
template <int ROWS>
__device__ __forceinline__ void stage_tile(const __bf16* g, int ld, __bf16* lds, int tid) {
#pragma unroll
    for (int r = 0; r < ROWS / 32; ++r) {
        int p = r * 4096 + tid * 16;
        int row = p >> 7;
        int kbp = p & 127;
        int kbl = kbp ^ ((row & 7) << 4);
        async_load16((const char*)(g + (size_t)row * ld) + kbl,
                     (char*)lds + (p & ~1023));
    }
}

__device__ __forceinline__ bf16x8 lds_frag(const __bf16* base, int row, int kb) {
    return *(const bf16x8*)((const char*)base + (row << 7) + (kb ^ ((row & 7) << 4)));
}

__device__ __forceinline__ unsigned cvtpk(float a, float b) {
    unsigned d;
    asm("v_cvt_pk_bf16_f32 %0, %1, %2" : "=v"(d) : "v"(a), "v"(b));
    return d;
}
__device__ __forceinline__ void pswap(unsigned& a, unsigned& b) {
    asm("v_permlane32_swap_b32 %0, %1" : "+v"(a), "+v"(b));
}

// ---------------- prep kernels ----------------

__global__ __launch_bounds__(256) void cvt3_kernel(const float* __restrict__ q,
                                                   const float* __restrict__ k,
                                                   const float* __restrict__ v,
                                                   __bf16* __restrict__ qb,
                                                   __bf16* __restrict__ kb,
                                                   __bf16* __restrict__ vb) {
    int z = blockIdx.y;
    const float* src = z == 0 ? q : (z == 1 ? k : v);
    __bf16* dst = z == 0 ? qb : (z == 1 ? kb : vb);
    int i = blockIdx.x * 256 + threadIdx.x;
    f32x4 val = ((const f32x4*)src)[i];
    bf16x4 o;
    o[0] = (__bf16)val[0]; o[1] = (__bf16)val[1];
    o[2] = (__bf16)val[2]; o[3] = (__bf16)val[3];
    ((bf16x4*)dst)[i] = o;
}

__global__ __launch_bounds__(256) void flags_init(unsigned* __restrict__ flags) {
    int t = threadIdx.x;
#pragma unroll
    for (int k = 0; k < 4; ++k) flags[t + k * 256] = 0u;
}

// Per-(b, q/128, kv/64) nonzero flags from the f32 mask (zero mask => 0 atomics)
__global__ __launch_bounds__(256) void mask_flags(const float* __restrict__ m,
                                                  unsigned* __restrict__ flags) {
    int i = blockIdx.x * 256 + threadIdx.x;    // over B*S*S/4 = 2,097,152
    f32x4 v = ((const f32x4*)m)[i];
    bool nz = (v[0] != 0.f) | (v[1] != 0.f) | (v[2] != 0.f) | (v[3] != 0.f);
    if (nz) {
        size_t i4 = (size_t)i * 4;
        int b = (int)(i4 >> 22);
        int rem = (int)(i4 & 4194303);
        int qq = rem >> 11, kv = rem & 2047;
        atomicOr(flags + (b * 16 + (qq >> 7)) * 32 + (kv >> 6), 1u);
    }
}

__global__ __launch_bounds__(256) void pack_wqkv(const float* __restrict__ Wq,
                                                 const float* __restrict__ Wk,
                                                 const float* __restrict__ Wv,
                                                 __bf16* __restrict__ out) {
    __shared__ __bf16 T[64][72];
    int tid = threadIdx.x;
    int k0 = blockIdx.x * 64, h = blockIdx.y, z = blockIdx.z;
    const float* W = z == 0 ? Wq : (z == 1 ? Wk : Wv);
#pragma unroll
    for (int it = 0; it < 4; ++it) {
        int idx = it * 1024 + tid * 4;
        int r = idx >> 6, e = idx & 63;
        f32x4 val = *(const f32x4*)(W + ((size_t)h * 1024 + k0 + r) * 64 + e);
#pragma unroll
        for (int j = 0; j < 4; ++j) T[r][e + j] = (__bf16)val[j];
    }
    __syncthreads();
    int e2 = tid >> 2, kc = (tid & 3) * 16;
    bf16x8 o0, o1;
#pragma unroll
    for (int i = 0; i < 8; ++i) { o0[i] = T[kc + i][e2]; o1[i] = T[kc + 8 + i][e2]; }
    __bf16* dst = out + ((size_t)z << 20) + (size_t)(h * 64 + e2) * 1024 + k0 + kc;
    *(bf16x8*)dst = o0;
    *(bf16x8*)(dst + 8) = o1;
}

__global__ __launch_bounds__(256) void pack_wo(const float* __restrict__ Wo,
                                               __bf16* __restrict__ out) {
    __shared__ __bf16 T[64][72];
    int tid = threadIdx.x;
    int k0 = blockIdx.x * 64, n0 = blockIdx.y * 64;
#pragma unroll
    for (int it = 0; it < 4; ++it) {
        int idx = it * 1024 + tid * 4;
        int r = idx >> 6, e = idx & 63;
        f32x4 val = *(const f32x4*)(Wo + (size_t)(k0 + r) * 1024 + n0 + e);
#pragma unroll
        for (int j = 0; j < 4; ++j) T[r][e + j] = (__bf16)val[j];
    }
    __syncthreads();
    int e2 = tid >> 2, kc = (tid & 3) * 16;
    bf16x8 o0, o1;
#pragma unroll
    for (int i = 0; i < 8; ++i) { o0[i] = T[kc + i][e2]; o1[i] = T[kc + 8 + i][e2]; }
    __bf16* dst = out + (size_t)(n0 + e2) * 1024 + k0 + kc;
    *(bf16x8*)dst = o0;
    *(bf16x8*)(dst + 8) = o1;
}

// vh [B,S,D] bf16 -> vT [B,H,HD,S] bf16
__global__ __launch_bounds__(256) void vtrans(const __bf16* __restrict__ vh,
                                              __bf16* __restrict__ vT) {
    __shared__ __bf16 T[64][72];
    int tid = threadIdx.x;
    int s0 = blockIdx.x * 64, bh = blockIdx.y, b = bh >> 4, h = bh & 15;
#pragma unroll
    for (int it = 0; it < 2; ++it) {
        int idx = it * 2048 + tid * 8;
        int r = idx >> 6, e0 = idx & 63;
        bf16x8 val = *(const bf16x8*)(vh + ((size_t)b * 2048 + s0 + r) * 1024 + h * 64 + e0);
#pragma unroll
        for (int j = 0; j < 8; ++j) T[r][e0 + j] = val[j];
    }
    __syncthreads();
    int e = tid >> 2, sc = (tid & 3) * 16;
    bf16x8 o0, o1;
#pragma unroll
    for (int i = 0; i < 8; ++i) { o0[i] = T[sc + i][e]; o1[i] = T[sc + 8 + i][e]; }
    __bf16* dst = vT + ((size_t)bh * 64 + e) * 2048 + s0 + sc;
    *(bf16x8*)dst = o0;
    *(bf16x8*)(dst + 8) = o1;
}

// ---------------- fused QKV GEMM ----------------
__global__ __launch_bounds__(256) void gemm_qkv(
    const __bf16* __restrict__ qb, const __bf16* __restrict__ kb,
    const __bf16* __restrict__ vb, const __bf16* __restrict__ w3,
    const float* __restrict__ bq, const float* __restrict__ bk,
    const float* __restrict__ bv,
    __bf16* __restrict__ qo, __bf16* __restrict__ ko, __bf16* __restrict__ vo) {
    __shared__ __bf16 As[128 * 64];
    __shared__ __bf16 Bs[128 * 64];
    int z = blockIdx.z;
    const __bf16* A = z == 0 ? qb : (z == 1 ? kb : vb);
    const __bf16* Bt = w3 + ((size_t)z << 20);
    const float* bias = z == 0 ? bq : (z == 1 ? bk : bv);
    __bf16* dst = z == 0 ? qo : (z == 1 ? ko : vo);
    float sc = z == 0 ? QSCL : 1.0f;

    int tid = threadIdx.x;
    int w = tid >> 6, lane = tid & 63, lg = lane >> 4, lr = lane & 15;
    int wr = (w >> 1) * 64, wc = (w & 1) * 64;
    int m0 = blockIdx.y * 128, n0 = blockIdx.x * 128;
    f32x4 acc[4][4] = {};
    for (int k0 = 0; k0 < 1024; k0 += 64) {
        __syncthreads();
        stage_tile<128>(A + (size_t)m0 * 1024 + k0, 1024, As, tid);
        stage_tile<128>(Bt + (size_t)n0 * 1024 + k0, 1024, Bs, tid);
        __syncthreads();
#pragma unroll
        for (int kk = 0; kk < 2; ++kk) {
            bf16x8 af[4], bfr[4];
#pragma unroll
            for (int t = 0; t < 4; ++t) {
                af[t] = lds_frag(As, wr + t * 16 + lr, lg * 16 + kk * 64);
                bfr[t] = lds_frag(Bs, wc + t * 16 + lr, lg * 16 + kk * 64);
            }
#pragma unroll
            for (int i = 0; i < 4; ++i)
#pragma unroll
                for (int j = 0; j < 4; ++j)
                    acc[i][j] = __builtin_amdgcn_mfma_f32_16x16x32_bf16(
                        af[i], bfr[j], acc[i][j], 0, 0, 0);
        }
    }
#pragma unroll
    for (int i = 0; i < 4; ++i) {
        int mb = m0 + wr + i * 16 + lg * 4;
#pragma unroll
        for (int j = 0; j < 4; ++j) {
            int n = n0 + wc + j * 16 + lr;
            float bvv = bias[n];
#pragma unroll
            for (int r = 0; r < 4; ++r)
                dst[(size_t)(mb + r) * 1024 + n] = (__bf16)((acc[i][j][r] + bvv) * sc);
        }
    }
}

// ---------------- final GEMM + GELU (64x128 tile) ----------------
__global__ __launch_bounds__(256) void gemm_out(const __bf16* __restrict__ A,
                                                const __bf16* __restrict__ Bt,
                                                const float* __restrict__ bias,
                                                float* __restrict__ dst) {
    __shared__ __bf16 As[64 * 64];
    __shared__ __bf16 Bs[128 * 64];
    int tid = threadIdx.x;
    int w = tid >> 6, lane = tid & 63, lg = lane >> 4, lr = lane & 15;
    int wr = (w >> 1) * 32, wc = (w & 1) * 64;
    int m0 = blockIdx.y * 64, n0 = blockIdx.x * 128;
    f32x4 acc[2][4] = {};
    for (int k0 = 0; k0 < 1024; k0 += 64) {
        __syncthreads();
        stage_tile<64>(A + (size_t)m0 * 1024 + k0, 1024, As, tid);
        stage_tile<128>(Bt + (size_t)n0 * 1024 + k0, 1024, Bs, tid);
        __syncthreads();
#pragma unroll
        for (int kk = 0; kk < 2; ++kk) {
            bf16x8 af[2], bfr[4];
#pragma unroll
            for (int t = 0; t < 2; ++t)
                af[t] = lds_frag(As, wr + t * 16 + lr, lg * 16 + kk * 64);
#pragma unroll
            for (int t = 0; t < 4; ++t)
                bfr[t] = lds_frag(Bs, wc + t * 16 + lr, lg * 16 + kk * 64);
#pragma unroll
            for (int i = 0; i < 2; ++i)
#pragma unroll
                for (int j = 0; j < 4; ++j)
                    acc[i][j] = __builtin_amdgcn_mfma_f32_16x16x32_bf16(
                        af[i], bfr[j], acc[i][j], 0, 0, 0);
        }
    }
#pragma unroll
    for (int i = 0; i < 2; ++i) {
        int mb = m0 + wr + i * 16 + lg * 4;
#pragma unroll
        for (int j = 0; j < 4; ++j) {
            int n = n0 + wc + j * 16 + lr;
            float bvv = bias[n];
#pragma unroll
            for (int r = 0; r < 4; ++r) {
                float v = acc[i][j][r] + bvv;
                float g = v / (1.f + exp2f(GELC * v));
                dst[(size_t)(mb + r) * 1024 + n] = g;
            }
        }
    }
}

// ---------------- flash attention: block-level kv-split, cheap combine ------
// grid (S/128, B*H, 2); 4 waves x 32 q-rows. Block z sweeps kv [z*1024,+1024)
// in 16 64-tiles (LDS dbuf K/V). Max-free log2 softmax => partials additive;
// partial O stored as coalesced bf16 (one writer per address), partial l as
// plain f32 stores. Mask: flag-gated direct f32 loads.
__global__ __launch_bounds__(256) void attn_kernel(
    const __bf16* __restrict__ qs, const __bf16* __restrict__ ks,
    const __bf16* __restrict__ vT, const float* __restrict__ mask,
    const unsigned* __restrict__ flags,
    __bf16* __restrict__ Op0, __bf16* __restrict__ Op1,
    float* __restrict__ lacc) {
    __shared__ __bf16 Ks[2][64 * 64];
    __shared__ __bf16 Vs[2][64 * 64];
    int tid = threadIdx.x;
    int w = tid >> 6, l = tid & 63;
    int q31 = l & 31, hi = l >> 5;
    int bh = blockIdx.y, b = bh >> 4, h = bh & 15;
    int qt = blockIdx.x;
    int qw = qt * 128 + w * 32;
    int z = blockIdx.z, kvbase = z << 10;

    // Q frags (B-operand): lane holds Q[q=qw+q31][d = kk*16 + hi*8 + j]
    const __bf16* Qp = qs + ((size_t)b * 2048 + qw + q31) * 1024 + h * 64 + hi * 8;
    bf16x8 qf[4];
#pragma unroll
    for (int kk = 0; kk < 4; ++kk) qf[kk] = *(const bf16x8*)(Qp + kk * 16);

    const __bf16* Kb = ks + ((size_t)b * 2048 + kvbase) * 1024 + h * 64;
    const __bf16* Vb = vT + (size_t)bh * 64 * 2048 + kvbase;
    const float* mrow = mask + (size_t)b * 4194304 + (size_t)(qw + q31) * 2048 + kvbase + hi * 4;
    const unsigned* flg = flags + (b * 16 + qt) * 32 + z * 16;

    f32x16 O[2] = {};
    float l_acc = 0.f;

    stage_tile<64>(Kb, 1024, Ks[0], tid);
    stage_tile<64>(Vb, 2048, Vs[0], tid);

    for (int kt = 0; kt < 16; ++kt) {
        int buf = kt & 1;
        __syncthreads();   // buf staged (barrier drains vmcnt); buf^1 free
        if (kt < 15) {
            stage_tile<64>(Kb + (size_t)(kt + 1) * 64 * 1024, 1024, Ks[buf ^ 1], tid);
            stage_tile<64>(Vb + (kt + 1) * 64, 2048, Vs[buf ^ 1], tid);
        }
        // K frags from LDS: A[kv = mt*32 + q31][d = kk*16 + hi*8 ..+8]
        bf16x8 kf[2][4];
#pragma unroll
        for (int mt = 0; mt < 2; ++mt)
#pragma unroll
            for (int kk = 0; kk < 4; ++kk)
                kf[mt][kk] = lds_frag(Ks[buf], mt * 32 + q31, kk * 32 + hi * 16);
        f32x16 T[2] = {};
        __builtin_amdgcn_s_setprio(1);
#pragma unroll
        for (int kk = 0; kk < 4; ++kk)
#pragma unroll
            for (int mt = 0; mt < 2; ++mt)
                T[mt] = __builtin_amdgcn_mfma_f32_32x32x16_bf16(kf[mt][kk], qf[kk], T[mt], 0, 0, 0);
        __builtin_amdgcn_s_setprio(0);

        // flag-gated mask add (wave-uniform branch), then max-free exp2
        unsigned fl = __builtin_amdgcn_readfirstlane(flg[kt]);
        if (fl) {
#pragma unroll
            for (int mt = 0; mt < 2; ++mt)
#pragma unroll
                for (int g = 0; g < 4; ++g) {
                    f32x4 mk = *(const f32x4*)(mrow + kt * 64 + mt * 32 + g * 8);
#pragma unroll
                    for (int c = 0; c < 4; ++c)
                        T[mt][4 * g + c] = fmaf(mk[c], L2E, T[mt][4 * g + c]);
                }
        }
#pragma unroll
        for (int mt = 0; mt < 2; ++mt)
#pragma unroll
            for (int g = 0; g < 4; ++g) {
                float p0 = exp2f(T[mt][4 * g + 0]);
                float p1 = exp2f(T[mt][4 * g + 1]);
                float p2 = exp2f(T[mt][4 * g + 2]);
                float p3 = exp2f(T[mt][4 * g + 3]);
                l_acc += (p0 + p1) + (p2 + p3);
                T[mt][4 * g + 0] = p0; T[mt][4 * g + 1] = p1;
                T[mt][4 * g + 2] = p2; T[mt][4 * g + 3] = p3;
            }

        // P frags in-register: pf[kk][j] = P[q=q31][kv = kk*16 + hi*8 + j]
        bf16x8 pf[4];
#pragma unroll
        for (int kk = 0; kk < 4; ++kk) {
            int mt = kk >> 1;
            int gA = (2 * kk) & 3, gB = gA + 1;
            unsigned x0 = cvtpk(T[mt][4 * gA + 0], T[mt][4 * gA + 1]);
            unsigned x1 = cvtpk(T[mt][4 * gA + 2], T[mt][4 * gA + 3]);
            unsigned y0 = cvtpk(T[mt][4 * gB + 0], T[mt][4 * gB + 1]);
            unsigned y1 = cvtpk(T[mt][4 * gB + 2], T[mt][4 * gB + 3]);
            pswap(x0, y0);
            pswap(x1, y1);
            u32x4 packed; packed[0] = x0; packed[1] = x1; packed[2] = y0; packed[3] = y1;
            pf[kk] = __builtin_bit_cast(bf16x8, packed);
        }

        // V frags read late (lower peak VGPR)
        bf16x8 vf[2][4];
#pragma unroll
        for (int mt = 0; mt < 2; ++mt)
#pragma unroll
            for (int kk = 0; kk < 4; ++kk)
                vf[mt][kk] = lds_frag(Vs[buf], mt * 32 + q31, kk * 32 + hi * 16);

        __builtin_amdgcn_s_setprio(1);
#pragma unroll
        for (int kk = 0; kk < 4; ++kk)
#pragma unroll
            for (int mt = 0; mt < 2; ++mt)
                O[mt] = __builtin_amdgcn_mfma_f32_32x32x16_bf16(vf[mt][kk], pf[kk], O[mt], 0, 0, 0);
        __builtin_amdgcn_s_setprio(0);
    }

    // combine via plain coalesced stores (one writer per address)
    l_acc += __shfl_xor(l_acc, 32, 64);
    if (hi == 0)
        lacc[((size_t)z * 32 + b * 16 + h) * 2048 + qw + q31] = l_acc;
    __bf16* Ob = (z ? Op1 : Op0) + (((size_t)(b * 16 + h)) * 2048 + qw + q31) * 64 + hi * 4;
#pragma unroll
    for (int mt = 0; mt < 2; ++mt)
#pragma unroll
        for (int g = 0; g < 4; ++g) {
            bf16x4 o;
#pragma unroll
            for (int c = 0; c < 4; ++c) o[c] = (__bf16)O[mt][4 * g + c];
            *(bf16x4*)(Ob + mt * 32 + g * 8) = o;
        }
}

// normalize: x[b,s,h*64+e] = bf16((Op0+Op1)[b][h][s][e] / (l0+l1)[b][h][s])
__global__ __launch_bounds__(256) void attn_norm(const __bf16* __restrict__ Op0,
                                                 const __bf16* __restrict__ Op1,
                                                 const float* __restrict__ lacc,
                                                 __bf16* __restrict__ x) {
    int idx = blockIdx.x * 256 + threadIdx.x;   // 1,048,576 total
    int b = idx >> 19;
    int rem = idx & 524287;                     // h[4] s[11] e4[4]
    int h = rem >> 15;
    int s = (rem >> 4) & 2047;
    int e0 = (rem & 15) * 4;
    size_t base = (((size_t)(b * 16 + h)) * 2048 + s) * 64 + e0;
    bf16x4 a = *(const bf16x4*)(Op0 + base);
    bf16x4 c = *(const bf16x4*)(Op1 + base);
    size_t li = ((size_t)(b * 16 + h)) * 2048 + s;
    float inv = 1.0f / (lacc[li] + lacc[65536 + li]);
    bf16x4 r;
#pragma unroll
    for (int j = 0; j < 4; ++j)
        r[j] = (__bf16)(((float)a[j] + (float)c[j]) * inv);
    *(bf16x4*)(x + ((size_t)b * 2048 + s) * 1024 + h * 64 + e0) = r;
}

// ---------------- launch ----------------

extern "C" void kernel_launch(void* const* d_in, const int* in_sizes, int n_in,
                              void* d_out, int out_size, void* d_ws, size_t ws_size,
                              hipStream_t stream) {
    const float* q    = (const float*)d_in[0];
    const float* k    = (const float*)d_in[1];
    const float* v    = (const float*)d_in[2];
    const float* mask = (const float*)d_in[3];
    const float* Wq   = (const float*)d_in[4];
    const float* bq   = (const float*)d_in[5];
    const float* Wk   = (const float*)d_in[6];
    const float* bk   = (const float*)d_in[7];
    const float* Wv   = (const float*)d_in[8];
    const float* bv   = (const float*)d_in[9];
    const float* Wo   = (const float*)d_in[10];
    const float* bo   = (const float*)d_in[11];

    char* ws = (char*)d_ws;
    __bf16* qb  = (__bf16*)(ws + (0ull  << 20));   // -> vT after gemm_qkv
    __bf16* kb  = (__bf16*)(ws + (8ull  << 20));   // -> Opart z=0
    __bf16* vb  = (__bf16*)(ws + (16ull << 20));   // -> Opart z=1
    __bf16* w3  = (__bf16*)(ws + (24ull << 20));   // 6 MB
    __bf16* wo  = (__bf16*)(ws + (30ull << 20));   // 2 MB (live till end)
    __bf16* qhp = (__bf16*)(ws + (32ull << 20));
    __bf16* khp = (__bf16*)(ws + (40ull << 20));
    __bf16* vhp = (__bf16*)(ws + (48ull << 20));   // -> x after norm
    float*  laccp = (float*)(ws + (56ull << 20));                        // 512 KB
    unsigned* flagp = (unsigned*)(ws + (56ull << 20) + (512ull << 10));  // 4 KB
    __bf16* vTp = qb;
    __bf16* Op0 = kb;
    __bf16* Op1 = vb;
    __bf16* xp  = vhp;

    cvt3_kernel<<<dim3(4096, 3), 256, 0, stream>>>(q, k, v, qb, kb, vb);
    pack_wqkv<<<dim3(16, 16, 3), 256, 0, stream>>>(Wq, Wk, Wv, w3);
    pack_wo<<<dim3(16, 16), 256, 0, stream>>>(Wo, wo);
    flags_init<<<1, 256, 0, stream>>>(flagp);
    mask_flags<<<8192, 256, 0, stream>>>(mask, flagp);

    gemm_qkv<<<dim3(8, 32, 3), 256, 0, stream>>>(qb, kb, vb, w3, bq, bk, bv,
                                                 qhp, khp, vhp);
    vtrans<<<dim3(32, 32), 256, 0, stream>>>(vhp, vTp);

    attn_kernel<<<dim3(16, 32, 2), 256, 0, stream>>>(qhp, khp, vTp, mask, flagp,
                                                     Op0, Op1, laccp);
    attn_norm<<<4096, 256, 0, stream>>>(Op0, Op1, laccp, xp);

    gemm_out<<<dim3(8, 64), 256, 0, stream>>>(xp, wo, bo, (float*)d_out);
}

// Round 9
// 165.931 us; speedup vs baseline: 2.3463x; 1.0291x over previous
//
#include <hip/hip_runtime.h>
#include <stdint.h>

// MultiHeadedAttention: B=2,S=2048,D=1024,H=16,HD=64
// R9 = R8 + XCD-locality swizzles (T1):
//  - attn: 1D grid, all 16 q-tiles of a (bh,z) group + both z-halves of a bh
//    on ONE XCD (K/V/Q fetched once per XCD L2; was 8x replicated -> 74MB).
//  - gemm_qkv: grid (32m, 8n, 3z) so XCD = m%8 (A-panel L2-local; was 192MB).
//  - gemm_out: grid (64m, 8n) so XCD = m%8 (A 8MB once; was 64MB).
// Inner loops identical to R8 (passed, absmax 2.4e-4).
// Workspace map (MB): 0-8 qb->vT, 8-16 kb->Op0, 16-24 vb->Op1, 24-30 w3,
// 30-32 wo, 32-40 qh, 40-48 kh, 48-56 vh->x, 56+ lacc(512KB)+flags(4KB)

typedef __bf16 bf16x8 __attribute__((ext_vector_type(8)));
typedef __bf16 bf16x4 __attribute__((ext_vector_type(4)));
typedef float f32x4 __attribute__((ext_vector_type(4)));
typedef float f32x16 __attribute__((ext_vector_type(16)));
typedef unsigned u32x4 __attribute__((ext_vector_type(4)));

static constexpr float L2E  = 1.4426950408889634f;
static constexpr float QSCL = 0.18033688011112042f;   // 0.125 * log2(e)
static constexpr float GELC = -2.4554669595930157f;   // -1.702 * log2(e)

__device__ __forceinline__ void async_load16(const void* g, void* l) {
    __builtin_amdgcn_global_load_lds(
        (const __attribute__((address_space(1))) unsigned int*)(uintptr_t)g,
        (__attribute__((address_space(3))) unsigned int*)(unsigned int)(uintptr_t)l,
        16, 0, 0);
}

// Stage ROWS x 64-bf16 tile into LDS, phys = row*128 + (kb ^ ((row&7)<<4)).
template <int ROWS>
__device__ __forceinline__ void stage_tile(const __bf16* g, int ld, __bf16* lds, int tid) {
#pragma unroll
    for (int r = 0; r < ROWS / 32; ++r) {
        int p = r * 4096 + tid * 16;
        int row = p >> 7;
        int kbp = p & 127;
        int kbl = kbp ^ ((row & 7) << 4);
        async_load16((const char*)(g + (size_t)row * ld) + kbl,
                     (char*)lds + (p & ~1023));
    }
}

__device__ __forceinline__ bf16x8 lds_frag(const __bf16* base, int row, int kb) {
    return *(const bf16x8*)((const char*)base + (row << 7) + (kb ^ ((row & 7) << 4)));
}

__device__ __forceinline__ unsigned cvtpk(float a, float b) {
    unsigned d;
    asm("v_cvt_pk_bf16_f32 %0, %1, %2" : "=v"(d) : "v"(a), "v"(b));
    return d;
}
__device__ __forceinline__ void pswap(unsigned& a, unsigned& b) {
    asm("v_permlane32_swap_b32 %0, %1" : "+v"(a), "+v"(b));
}

// ---------------- prep kernels ----------------

__global__ __launch_bounds__(256) void cvt3_kernel(const float* __restrict__ q,
                                                   const float* __restrict__ k,
                                                   const float* __restrict__ v,
                                                   __bf16* __restrict__ qb,
                                                   __bf16* __restrict__ kb,
                                                   __bf16* __restrict__ vb) {
    int z = blockIdx.y;
    const float* src = z == 0 ? q : (z == 1 ? k : v);
    __bf16* dst = z == 0 ? qb : (z == 1 ? kb : vb);
    int i = blockIdx.x * 256 + threadIdx.x;
    f32x4 val = ((const f32x4*)src)[i];
    bf16x4 o;
    o[0] = (__bf16)val[0]; o[1] = (__bf16)val[1];
    o[2] = (__bf16)val[2]; o[3] = (__bf16)val[3];
    ((bf16x4*)dst)[i] = o;
}

__global__ __launch_bounds__(256) void flags_init(unsigned* __restrict__ flags) {
    int t = threadIdx.x;
#pragma unroll
    for (int k = 0; k < 4; ++k) flags[t + k * 256] = 0u;
}

// Per-(b, q/128, kv/64) nonzero flags from the f32 mask (zero mask => 0 atomics)
__global__ __launch_bounds__(256) void mask_flags(const float* __restrict__ m,
                                                  unsigned* __restrict__ flags) {
    int i = blockIdx.x * 256 + threadIdx.x;    // over B*S*S/4 = 2,097,152
    f32x4 v = ((const f32x4*)m)[i];
    bool nz = (v[0] != 0.f) | (v[1] != 0.f) | (v[2] != 0.f) | (v[3] != 0.f);
    if (nz) {
        size_t i4 = (size_t)i * 4;
        int b = (int)(i4 >> 22);
        int rem = (int)(i4 & 4194303);
        int qq = rem >> 11, kv = rem & 2047;
        atomicOr(flags + (b * 16 + (qq >> 7)) * 32 + (kv >> 6), 1u);
    }
}

__global__ __launch_bounds__(256) void pack_wqkv(const float* __restrict__ Wq,
                                                 const float* __restrict__ Wk,
                                                 const float* __restrict__ Wv,
                                                 __bf16* __restrict__ out) {
    __shared__ __bf16 T[64][72];
    int tid = threadIdx.x;
    int k0 = blockIdx.x * 64, h = blockIdx.y, z = blockIdx.z;
    const float* W = z == 0 ? Wq : (z == 1 ? Wk : Wv);
#pragma unroll
    for (int it = 0; it < 4; ++it) {
        int idx = it * 1024 + tid * 4;
        int r = idx >> 6, e = idx & 63;
        f32x4 val = *(const f32x4*)(W + ((size_t)h * 1024 + k0 + r) * 64 + e);
#pragma unroll
        for (int j = 0; j < 4; ++j) T[r][e + j] = (__bf16)val[j];
    }
    __syncthreads();
    int e2 = tid >> 2, kc = (tid & 3) * 16;
    bf16x8 o0, o1;
#pragma unroll
    for (int i = 0; i < 8; ++i) { o0[i] = T[kc + i][e2]; o1[i] = T[kc + 8 + i][e2]; }
    __bf16* dst = out + ((size_t)z << 20) + (size_t)(h * 64 + e2) * 1024 + k0 + kc;
    *(bf16x8*)dst = o0;
    *(bf16x8*)(dst + 8) = o1;
}

__global__ __launch_bounds__(256) void pack_wo(const float* __restrict__ Wo,
                                               __bf16* __restrict__ out) {
    __shared__ __bf16 T[64][72];
    int tid = threadIdx.x;
    int k0 = blockIdx.x * 64, n0 = blockIdx.y * 64;
#pragma unroll
    for (int it = 0; it < 4; ++it) {
        int idx = it * 1024 + tid * 4;
        int r = idx >> 6, e = idx & 63;
        f32x4 val = *(const f32x4*)(Wo + (size_t)(k0 + r) * 1024 + n0 + e);
#pragma unroll
        for (int j = 0; j < 4; ++j) T[r][e + j] = (__bf16)val[j];
    }
    __syncthreads();
    int e2 = tid >> 2, kc = (tid & 3) * 16;
    bf16x8 o0, o1;
#pragma unroll
    for (int i = 0; i < 8; ++i) { o0[i] = T[kc + i][e2]; o1[i] = T[kc + 8 + i][e2]; }
    __bf16* dst = out + (size_t)(n0 + e2) * 1024 + k0 + kc;
    *(bf16x8*)dst = o0;
    *(bf16x8*)(dst + 8) = o1;
}

// vh [B,S,D] bf16 -> vT [B,H,HD,S] bf16
__global__ __launch_bounds__(256) void vtrans(const __bf16* __restrict__ vh,
                                              __bf16* __restrict__ vT) {
    __shared__ __bf16 T[64][72];
    int tid = threadIdx.x;
    int s0 = blockIdx.x * 64, bh = blockIdx.y, b = bh >> 4, h = bh & 15;
#pragma unroll
    for (int it = 0; it < 2; ++it) {
        int idx = it * 2048 + tid * 8;
        int r = idx >> 6, e0 = idx & 63;
        bf16x8 val = *(const bf16x8*)(vh + ((size_t)b * 2048 + s0 + r) * 1024 + h * 64 + e0);
#pragma unroll
        for (int j = 0; j < 8; ++j) T[r][e0 + j] = val[j];
    }
    __syncthreads();
    int e = tid >> 2, sc = (tid & 3) * 16;
    bf16x8 o0, o1;
#pragma unroll
    for (int i = 0; i < 8; ++i) { o0[i] = T[sc + i][e]; o1[i] = T[sc + 8 + i][e]; }
    __bf16* dst = vT + ((size_t)bh * 64 + e) * 2048 + s0 + sc;
    *(bf16x8*)dst = o0;
    *(bf16x8*)(dst + 8) = o1;
}

// ---------------- fused QKV GEMM (grid: x=m 32, y=n 8, z=3; XCD = m%8) ------
__global__ __launch_bounds__(256) void gemm_qkv(
    const __bf16* __restrict__ qb, const __bf16* __restrict__ kb,
    const __bf16* __restrict__ vb, const __bf16* __restrict__ w3,
    const float* __restrict__ bq, const float* __restrict__ bk,
    const float* __restrict__ bv,
    __bf16* __restrict__ qo, __bf16* __restrict__ ko, __bf16* __restrict__ vo) {
    __shared__ __bf16 As[128 * 64];
    __shared__ __bf16 Bs[128 * 64];
    int z = blockIdx.z;
    const __bf16* A = z == 0 ? qb : (z == 1 ? kb : vb);
    const __bf16* Bt = w3 + ((size_t)z << 20);
    const float* bias = z == 0 ? bq : (z == 1 ? bk : bv);
    __bf16* dst = z == 0 ? qo : (z == 1 ? ko : vo);
    float sc = z == 0 ? QSCL : 1.0f;

    int tid = threadIdx.x;
    int w = tid >> 6, lane = tid & 63, lg = lane >> 4, lr = lane & 15;
    int wr = (w >> 1) * 64, wc = (w & 1) * 64;
    int m0 = blockIdx.x * 128, n0 = blockIdx.y * 128;   // m fastest -> XCD=m%8
    f32x4 acc[4][4] = {};
    for (int k0 = 0; k0 < 1024; k0 += 64) {
        __syncthreads();
        stage_tile<128>(A + (size_t)m0 * 1024 + k0, 1024, As, tid);
        stage_tile<128>(Bt + (size_t)n0 * 1024 + k0, 1024, Bs, tid);
        __syncthreads();
#pragma unroll
        for (int kk = 0; kk < 2; ++kk) {
            bf16x8 af[4], bfr[4];
#pragma unroll
            for (int t = 0; t < 4; ++t) {
                af[t] = lds_frag(As, wr + t * 16 + lr, lg * 16 + kk * 64);
                bfr[t] = lds_frag(Bs, wc + t * 16 + lr, lg * 16 + kk * 64);
            }
#pragma unroll
            for (int i = 0; i < 4; ++i)
#pragma unroll
                for (int j = 0; j < 4; ++j)
                    acc[i][j] = __builtin_amdgcn_mfma_f32_16x16x32_bf16(
                        af[i], bfr[j], acc[i][j], 0, 0, 0);
        }
    }
#pragma unroll
    for (int i = 0; i < 4; ++i) {
        int mb = m0 + wr + i * 16 + lg * 4;
#pragma unroll
        for (int j = 0; j < 4; ++j) {
            int n = n0 + wc + j * 16 + lr;
            float bvv = bias[n];
#pragma unroll
            for (int r = 0; r < 4; ++r)
                dst[(size_t)(mb + r) * 1024 + n] = (__bf16)((acc[i][j][r] + bvv) * sc);
        }
    }
}

// ---------------- final GEMM + GELU (grid: x=m 64, y=n 8; XCD = m%8) --------
__global__ __launch_bounds__(256) void gemm_out(const __bf16* __restrict__ A,
                                                const __bf16* __restrict__ Bt,
                                                const float* __restrict__ bias,
                                                float* __restrict__ dst) {
    __shared__ __bf16 As[64 * 64];
    __shared__ __bf16 Bs[128 * 64];
    int tid = threadIdx.x;
    int w = tid >> 6, lane = tid & 63, lg = lane >> 4, lr = lane & 15;
    int wr = (w >> 1) * 32, wc = (w & 1) * 64;
    int m0 = blockIdx.x * 64, n0 = blockIdx.y * 128;    // m fastest -> XCD=m%8
    f32x4 acc[2][4] = {};
    for (int k0 = 0; k0 < 1024; k0 += 64) {
        __syncthreads();
        stage_tile<64>(A + (size_t)m0 * 1024 + k0, 1024, As, tid);
        stage_tile<128>(Bt + (size_t)n0 * 1024 + k0, 1024, Bs, tid);
        __syncthreads();
#pragma unroll
        for (int kk = 0; kk < 2; ++kk) {
            bf16x8 af[2], bfr[4];
#pragma unroll
            for (int t = 0; t < 2; ++t)
                af[t] = lds_frag(As, wr + t * 16 + lr, lg * 16 + kk * 64);
#pragma unroll
            for (int t = 0; t < 4; ++t)
                bfr[t] = lds_frag(Bs, wc + t * 16 + lr, lg * 16 + kk * 64);
#pragma unroll
            for (int i = 0; i < 2; ++i)
#pragma unroll
                for (int j = 0; j < 4; ++j)
                    acc[i][j] = __builtin_amdgcn_mfma_f32_16x16x32_bf16(
                        af[i], bfr[j], acc[i][j], 0, 0, 0);
        }
    }
#pragma unroll
    for (int i = 0; i < 2; ++i) {
        int mb = m0 + wr + i * 16 + lg * 4;
#pragma unroll
        for (int j = 0; j < 4; ++j) {
            int n = n0 + wc + j * 16 + lr;
            float bvv = bias[n];
#pragma unroll
            for (int r = 0; r < 4; ++r) {
                float v = acc[i][j][r] + bvv;
                float g = v / (1.f + exp2f(GELC * v));
                dst[(size_t)(mb + r) * 1024 + n] = g;
            }
        }
    }
}

// ---------------- flash attention: kv-split + XCD-grouped 1D grid -----------
// 1D grid 1024. Decode: xcd=i&7, j=i>>3, group=(j>>4)*8+xcd, qt=j&15,
// bh=group&31, z=group>>5. All 16 q-tiles of a (bh,z) group AND both z-halves
// of a bh land on one XCD (blocks ≡ xcd mod 8) -> K/V/Q single L2 fetch/XCD.
__global__ __launch_bounds__(256) void attn_kernel(
    const __bf16* __restrict__ qs, const __bf16* __restrict__ ks,
    const __bf16* __restrict__ vT, const float* __restrict__ mask,
    const unsigned* __restrict__ flags,
    __bf16* __restrict__ Op0, __bf16* __restrict__ Op1,
    float* __restrict__ lacc) {
    __shared__ __bf16 Ks[2][64 * 64];
    __shared__ __bf16 Vs[2][64 * 64];
    int tid = threadIdx.x;
    int w = tid >> 6, l = tid & 63;
    int q31 = l & 31, hi = l >> 5;
    int i = blockIdx.x;
    int xcd = i & 7, j = i >> 3;
    int group = (j >> 4) * 8 + xcd;
    int qt = j & 15;
    int bh = group & 31, z = group >> 5;
    int b = bh >> 4, h = bh & 15;
    int qw = qt * 128 + w * 32;
    int kvbase = z << 10;

    // Q frags (B-operand): lane holds Q[q=qw+q31][d = kk*16 + hi*8 + j]
    const __bf16* Qp = qs + ((size_t)b * 2048 + qw + q31) * 1024 + h * 64 + hi * 8;
    bf16x8 qf[4];
#pragma unroll
    for (int kk = 0; kk < 4; ++kk) qf[kk] = *(const bf16x8*)(Qp + kk * 16);

    const __bf16* Kb = ks + ((size_t)b * 2048 + kvbase) * 1024 + h * 64;
    const __bf16* Vb = vT + (size_t)bh * 64 * 2048 + kvbase;
    const float* mrow = mask + (size_t)b * 4194304 + (size_t)(qw + q31) * 2048 + kvbase + hi * 4;
    const unsigned* flg = flags + (b * 16 + qt) * 32 + z * 16;

    f32x16 O[2] = {};
    float l_acc = 0.f;

    stage_tile<64>(Kb, 1024, Ks[0], tid);
    stage_tile<64>(Vb, 2048, Vs[0], tid);

    for (int kt = 0; kt < 16; ++kt) {
        int buf = kt & 1;
        __syncthreads();   // buf staged (barrier drains vmcnt); buf^1 free
        if (kt < 15) {
            stage_tile<64>(Kb + (size_t)(kt + 1) * 64 * 1024, 1024, Ks[buf ^ 1], tid);
            stage_tile<64>(Vb + (kt + 1) * 64, 2048, Vs[buf ^ 1], tid);
        }
        // K frags from LDS: A[kv = mt*32 + q31][d = kk*16 + hi*8 ..+8]
        bf16x8 kf[2][4];
#pragma unroll
        for (int mt = 0; mt < 2; ++mt)
#pragma unroll
            for (int kk = 0; kk < 4; ++kk)
                kf[mt][kk] = lds_frag(Ks[buf], mt * 32 + q31, kk * 32 + hi * 16);
        f32x16 T[2] = {};
        __builtin_amdgcn_s_setprio(1);
#pragma unroll
        for (int kk = 0; kk < 4; ++kk)
#pragma unroll
            for (int mt = 0; mt < 2; ++mt)
                T[mt] = __builtin_amdgcn_mfma_f32_32x32x16_bf16(kf[mt][kk], qf[kk], T[mt], 0, 0, 0);
        __builtin_amdgcn_s_setprio(0);

        // flag-gated mask add (wave-uniform branch), then max-free exp2
        unsigned fl = __builtin_amdgcn_readfirstlane(flg[kt]);
        if (fl) {
#pragma unroll
            for (int mt = 0; mt < 2; ++mt)
#pragma unroll
                for (int g = 0; g < 4; ++g) {
                    f32x4 mk = *(const f32x4*)(mrow + kt * 64 + mt * 32 + g * 8);
#pragma unroll
                    for (int c = 0; c < 4; ++c)
                        T[mt][4 * g + c] = fmaf(mk[c], L2E, T[mt][4 * g + c]);
                }
        }
#pragma unroll
        for (int mt = 0; mt < 2; ++mt)
#pragma unroll
            for (int g = 0; g < 4; ++g) {
                float p0 = exp2f(T[mt][4 * g + 0]);
                float p1 = exp2f(T[mt][4 * g + 1]);
                float p2 = exp2f(T[mt][4 * g + 2]);
                float p3 = exp2f(T[mt][4 * g + 3]);
                l_acc += (p0 + p1) + (p2 + p3);
                T[mt][4 * g + 0] = p0; T[mt][4 * g + 1] = p1;
                T[mt][4 * g + 2] = p2; T[mt][4 * g + 3] = p3;
            }

        // P frags in-register: pf[kk][j] = P[q=q31][kv = kk*16 + hi*8 + j]
        bf16x8 pf[4];
#pragma unroll
        for (int kk = 0; kk < 4; ++kk) {
            int mt = kk >> 1;
            int gA = (2 * kk) & 3, gB = gA + 1;
            unsigned x0 = cvtpk(T[mt][4 * gA + 0], T[mt][4 * gA + 1]);
            unsigned x1 = cvtpk(T[mt][4 * gA + 2], T[mt][4 * gA + 3]);
            unsigned y0 = cvtpk(T[mt][4 * gB + 0], T[mt][4 * gB + 1]);
            unsigned y1 = cvtpk(T[mt][4 * gB + 2], T[mt][4 * gB + 3]);
            pswap(x0, y0);
            pswap(x1, y1);
            u32x4 packed; packed[0] = x0; packed[1] = x1; packed[2] = y0; packed[3] = y1;
            pf[kk] = __builtin_bit_cast(bf16x8, packed);
        }

        // V frags read late (lower peak VGPR)
        bf16x8 vf[2][4];
#pragma unroll
        for (int mt = 0; mt < 2; ++mt)
#pragma unroll
            for (int kk = 0; kk < 4; ++kk)
                vf[mt][kk] = lds_frag(Vs[buf], mt * 32 + q31, kk * 32 + hi * 16);

        __builtin_amdgcn_s_setprio(1);
#pragma unroll
        for (int kk = 0; kk < 4; ++kk)
#pragma unroll
            for (int mt = 0; mt < 2; ++mt)
                O[mt] = __builtin_amdgcn_mfma_f32_32x32x16_bf16(vf[mt][kk], pf[kk], O[mt], 0, 0, 0);
        __builtin_amdgcn_s_setprio(0);
    }

    // combine via plain coalesced stores (one writer per address)
    l_acc += __shfl_xor(l_acc, 32, 64);
    if (hi == 0)
        lacc[((size_t)z * 32 + b * 16 + h) * 2048 + qw + q31] = l_acc;
    __bf16* Ob = (z ? Op1 : Op0) + (((size_t)(b * 16 + h)) * 2048 + qw + q31) * 64 + hi * 4;
#pragma unroll
    for (int mt = 0; mt < 2; ++mt)
#pragma unroll
        for (int g = 0; g < 4; ++g) {
            bf16x4 o;
#pragma unroll
            for (int c = 0; c < 4; ++c) o[c] = (__bf16)O[mt][4 * g + c];
            *(bf16x4*)(Ob + mt * 32 + g * 8) = o;
        }
}

// normalize: x[b,s,h*64+e] = bf16((Op0+Op1)[b][h][s][e] / (l0+l1)[b][h][s])
__global__ __launch_bounds__(256) void attn_norm(const __bf16* __restrict__ Op0,
                                                 const __bf16* __restrict__ Op1,
                                                 const float* __restrict__ lacc,
                                                 __bf16* __restrict__ x) {
    int idx = blockIdx.x * 256 + threadIdx.x;   // 1,048,576 total
    int b = idx >> 19;
    int rem = idx & 524287;                     // h[4] s[11] e4[4]
    int h = rem >> 15;
    int s = (rem >> 4) & 2047;
    int e0 = (rem & 15) * 4;
    size_t base = (((size_t)(b * 16 + h)) * 2048 + s) * 64 + e0;
    bf16x4 a = *(const bf16x4*)(Op0 + base);
    bf16x4 c = *(const bf16x4*)(Op1 + base);
    size_t li = ((size_t)(b * 16 + h)) * 2048 + s;
    float inv = 1.0f / (lacc[li] + lacc[65536 + li]);
    bf16x4 r;
#pragma unroll
    for (int j = 0; j < 4; ++j)
        r[j] = (__bf16)(((float)a[j] + (float)c[j]) * inv);
    *(bf16x4*)(x + ((size_t)b * 2048 + s) * 1024 + h * 64 + e0) = r;
}

// ---------------- launch ----------------

extern "C" void kernel_launch(void* const* d_in, const int* in_sizes, int n_in,
                              void* d_out, int out_size, void* d_ws, size_t ws_size,
                              hipStream_t stream) {
    const float* q    = (const float*)d_in[0];
    const float* k    = (const float*)d_in[1];
    const float* v    = (const float*)d_in[2];
    const float* mask = (const float*)d_in[3];
    const float* Wq   = (const float*)d_in[4];
    const float* bq   = (const float*)d_in[5];
    const float* Wk   = (const float*)d_in[6];
    const float* bk   = (const float*)d_in[7];
    const float* Wv   = (const float*)d_in[8];
    const float* bv   = (const float*)d_in[9];
    const float* Wo   = (const float*)d_in[10];
    const float* bo   = (const float*)d_in[11];

    char* ws = (char*)d_ws;
    __bf16* qb  = (__bf16*)(ws + (0ull  << 20));   // -> vT after gemm_qkv
    __bf16* kb  = (__bf16*)(ws + (8ull  << 20));   // -> Opart z=0
    __bf16* vb  = (__bf16*)(ws + (16ull << 20));   // -> Opart z=1
    __bf16* w3  = (__bf16*)(ws + (24ull << 20));   // 6 MB
    __bf16* wo  = (__bf16*)(ws + (30ull << 20));   // 2 MB (live till end)
    __bf16* qhp = (__bf16*)(ws + (32ull << 20));
    __bf16* khp = (__bf16*)(ws + (40ull << 20));
    __bf16* vhp = (__bf16*)(ws + (48ull << 20));   // -> x after norm
    float*  laccp = (float*)(ws + (56ull << 20));                        // 512 KB
    unsigned* flagp = (unsigned*)(ws + (56ull << 20) + (512ull << 10));  // 4 KB
    __bf16* vTp = qb;
    __bf16* Op0 = kb;
    __bf16* Op1 = vb;
    __bf16* xp  = vhp;

    cvt3_kernel<<<dim3(4096, 3), 256, 0, stream>>>(q, k, v, qb, kb, vb);
    pack_wqkv<<<dim3(16, 16, 3), 256, 0, stream>>>(Wq, Wk, Wv, w3);
    pack_wo<<<dim3(16, 16), 256, 0, stream>>>(Wo, wo);
    flags_init<<<1, 256, 0, stream>>>(flagp);
    mask_flags<<<8192, 256, 0, stream>>>(mask, flagp);

    gemm_qkv<<<dim3(32, 8, 3), 256, 0, stream>>>(qb, kb, vb, w3, bq, bk, bv,
                                                 qhp, khp, vhp);
    vtrans<<<dim3(32, 32), 256, 0, stream>>>(vhp, vTp);

    attn_kernel<<<dim3(1024), 256, 0, stream>>>(qhp, khp, vTp, mask, flagp,
                                                Op0, Op1, laccp);
    attn_norm<<<4096, 256, 0, stream>>>(Op0, Op1, laccp, xp);

    gemm_out<<<dim3(64, 8), 256, 0, stream>>>(xp, wo, bo, (float*)d_out);
}

// Round 10
// 165.695 us; speedup vs baseline: 2.3496x; 1.0014x over previous
//
#include <hip/hip_runtime.h>
#include <stdint.h>

// MultiHeadedAttention: B=2,S=2048,D=1024,H=16,HD=64
// R10: LDS-FREE attention. Q/K/V pre-packed into MFMA-fragment stream order
// (per (b,h): [s-block32][kk][hi][lane31][8]; V: [kv-tile64][mt][kk][hi][e31][8])
// so each fragment = one coalesced 1KB global_load_dwordx4 (L2-local via R9's
// XCD swizzle). No barriers, no ds_read, no bank conflicts; K reg-prefetched
// one tile ahead; V loads issued before the exp2 block (latency hidden).
// Everything else = R9 (kv-split z=2, cheap bf16-partial combine, flag-gated
// mask, max-free log2 softmax, XCD-swizzled GEMMs).
// Workspace map (MB): 0-8 qb->Qp, 8-16 kb->Vp, 16-24 vb->Kp, 24-30 w3,
// 30-32 wo, 32-40 qh->Op0, 40-48 kh->Op1, 48-56 vh->x, 56+ lacc+flags

typedef __bf16 bf16x8 __attribute__((ext_vector_type(8)));
typedef __bf16 bf16x4 __attribute__((ext_vector_type(4)));
typedef float f32x4 __attribute__((ext_vector_type(4)));
typedef float f32x16 __attribute__((ext_vector_type(16)));
typedef unsigned u32x4 __attribute__((ext_vector_type(4)));

static constexpr float L2E  = 1.4426950408889634f;
static constexpr float QSCL = 0.18033688011112042f;   // 0.125 * log2(e)
static constexpr float GELC = -2.4554669595930157f;   // -1.702 * log2(e)

__device__ __forceinline__ void async_load16(const void* g, void* l) {
    __builtin_amdgcn_global_load_lds(
        (const __attribute__((address_space(1))) unsigned int*)(uintptr_t)g,
        (__attribute__((address_space(3))) unsigned int*)(unsigned int)(uintptr_t)l,
        16, 0, 0);
}

// Stage ROWS x 64-bf16 tile into LDS, phys = row*128 + (kb ^ ((row&7)<<4)).
template <int ROWS>
__device__ __forceinline__ void stage_tile(const __bf16* g, int ld, __bf16* lds, int tid) {
#pragma unroll
    for (int r = 0; r < ROWS / 32; ++r) {
        int p = r * 4096 + tid * 16;
        int row = p >> 7;
        int kbp = p & 127;
        int kbl = kbp ^ ((row & 7) << 4);
        async_load16((const char*)(g + (size_t)row * ld) + kbl,
                     (char*)lds + (p & ~1023));
    }
}

__device__ __forceinline__ bf16x8 lds_frag(const __bf16* base, int row, int kb) {
    return *(const bf16x8*)((const char*)base + (row << 7) + (kb ^ ((row & 7) << 4)));
}

__device__ __forceinline__ unsigned cvtpk(float a, float b) {
    unsigned d;
    asm("v_cvt_pk_bf16_f32 %0, %1, %2" : "=v"(d) : "v"(a), "v"(b));
    return d;
}
__device__ __forceinline__ void pswap(unsigned& a, unsigned& b) {
    asm("v_permlane32_swap_b32 %0, %1" : "+v"(a), "+v"(b));
}

// ---------------- prep kernels ----------------

__global__ __launch_bounds__(256) void cvt3_kernel(const float* __restrict__ q,
                                                   const float* __restrict__ k,
                                                   const float* __restrict__ v,
                                                   __bf16* __restrict__ qb,
                                                   __bf16* __restrict__ kb,
                                                   __bf16* __restrict__ vb) {
    int z = blockIdx.y;
    const float* src = z == 0 ? q : (z == 1 ? k : v);
    __bf16* dst = z == 0 ? qb : (z == 1 ? kb : vb);
    int i = blockIdx.x * 256 + threadIdx.x;
    f32x4 val = ((const f32x4*)src)[i];
    bf16x4 o;
    o[0] = (__bf16)val[0]; o[1] = (__bf16)val[1];
    o[2] = (__bf16)val[2]; o[3] = (__bf16)val[3];
    ((bf16x4*)dst)[i] = o;
}

__global__ __launch_bounds__(256) void flags_init(unsigned* __restrict__ flags) {
    int t = threadIdx.x;
#pragma unroll
    for (int k = 0; k < 4; ++k) flags[t + k * 256] = 0u;
}

// Per-(b, q/128, kv/64) nonzero flags from the f32 mask (zero mask => 0 atomics)
__global__ __launch_bounds__(256) void mask_flags(const float* __restrict__ m,
                                                  unsigned* __restrict__ flags) {
    int i = blockIdx.x * 256 + threadIdx.x;    // over B*S*S/4 = 2,097,152
    f32x4 v = ((const f32x4*)m)[i];
    bool nz = (v[0] != 0.f) | (v[1] != 0.f) | (v[2] != 0.f) | (v[3] != 0.f);
    if (nz) {
        size_t i4 = (size_t)i * 4;
        int b = (int)(i4 >> 22);
        int rem = (int)(i4 & 4194303);
        int qq = rem >> 11, kv = rem & 2047;
        atomicOr(flags + (b * 16 + (qq >> 7)) * 32 + (kv >> 6), 1u);
    }
}

__global__ __launch_bounds__(256) void pack_wqkv(const float* __restrict__ Wq,
                                                 const float* __restrict__ Wk,
                                                 const float* __restrict__ Wv,
                                                 __bf16* __restrict__ out) {
    __shared__ __bf16 T[64][72];
    int tid = threadIdx.x;
    int k0 = blockIdx.x * 64, h = blockIdx.y, z = blockIdx.z;
    const float* W = z == 0 ? Wq : (z == 1 ? Wk : Wv);
#pragma unroll
    for (int it = 0; it < 4; ++it) {
        int idx = it * 1024 + tid * 4;
        int r = idx >> 6, e = idx & 63;
        f32x4 val = *(const f32x4*)(W + ((size_t)h * 1024 + k0 + r) * 64 + e);
#pragma unroll
        for (int j = 0; j < 4; ++j) T[r][e + j] = (__bf16)val[j];
    }
    __syncthreads();
    int e2 = tid >> 2, kc = (tid & 3) * 16;
    bf16x8 o0, o1;
#pragma unroll
    for (int i = 0; i < 8; ++i) { o0[i] = T[kc + i][e2]; o1[i] = T[kc + 8 + i][e2]; }
    __bf16* dst = out + ((size_t)z << 20) + (size_t)(h * 64 + e2) * 1024 + k0 + kc;
    *(bf16x8*)dst = o0;
    *(bf16x8*)(dst + 8) = o1;
}

__global__ __launch_bounds__(256) void pack_wo(const float* __restrict__ Wo,
                                               __bf16* __restrict__ out) {
    __shared__ __bf16 T[64][72];
    int tid = threadIdx.x;
    int k0 = blockIdx.x * 64, n0 = blockIdx.y * 64;
#pragma unroll
    for (int it = 0; it < 4; ++it) {
        int idx = it * 1024 + tid * 4;
        int r = idx >> 6, e = idx & 63;
        f32x4 val = *(const f32x4*)(Wo + (size_t)(k0 + r) * 1024 + n0 + e);
#pragma unroll
        for (int j = 0; j < 4; ++j) T[r][e + j] = (__bf16)val[j];
    }
    __syncthreads();
    int e2 = tid >> 2, kc = (tid & 3) * 16;
    bf16x8 o0, o1;
#pragma unroll
    for (int i = 0; i < 8; ++i) { o0[i] = T[kc + i][e2]; o1[i] = T[kc + 8 + i][e2]; }
    __bf16* dst = out + (size_t)(n0 + e2) * 1024 + k0 + kc;
    *(bf16x8*)dst = o0;
    *(bf16x8*)(dst + 8) = o1;
}

// src [B,S,D] bf16 -> per (b,h): [s/32][kk(4)][hi(2)][q31(32)][8] fragment order
// (frag load for lane l = hi*32+q31: base + kk*512 + l*8, one 1KB wave read)
__global__ __launch_bounds__(256) void qkpack(const __bf16* __restrict__ qh,
                                              const __bf16* __restrict__ kh,
                                              __bf16* __restrict__ Qp,
                                              __bf16* __restrict__ Kp) {
    __shared__ __bf16 T[64][72];
    int tid = threadIdx.x;
    int s0 = blockIdx.x * 64, bh = blockIdx.y, b = bh >> 4, h = bh & 15;
    const __bf16* src = blockIdx.z ? kh : qh;
    __bf16* out = blockIdx.z ? Kp : Qp;
#pragma unroll
    for (int it = 0; it < 2; ++it) {
        int idx = it * 2048 + tid * 8;
        int r = idx >> 6, e0 = idx & 63;
        bf16x8 val = *(const bf16x8*)(src + ((size_t)b * 2048 + s0 + r) * 1024 + h * 64 + e0);
#pragma unroll
        for (int j = 0; j < 8; ++j) T[r][e0 + j] = val[j];
    }
    __syncthreads();
#pragma unroll
    for (int u0 = 0; u0 < 2; ++u0) {
        int u = u0 * 256 + tid;            // chunk 0..511
        int sb = u >> 8, rem = u & 255;    // [sb32][kk][hi][q31]
        int kk = rem >> 6, hi = (rem >> 5) & 1, q31 = rem & 31;
        bf16x8 o;
#pragma unroll
        for (int j = 0; j < 8; ++j) o[j] = T[sb * 32 + q31][kk * 16 + hi * 8 + j];
        *(bf16x8*)(out + ((size_t)bh * 64 + blockIdx.x * 2 + sb) * 2048 + rem * 8) = o;
    }
}

// vh [B,S,D] bf16 -> per (b,h): [kv-tile64][mt(2)][kk(4)][hi(2)][e31(32)][8]
// (vf[mt][kk] lane l = hi*32+e31: tile*4096 + (mt*4+kk)*512 + l*8)
__global__ __launch_bounds__(256) void vpack(const __bf16* __restrict__ vh,
                                             __bf16* __restrict__ Vp) {
    __shared__ __bf16 T[64][72];
    int tid = threadIdx.x;
    int s0 = blockIdx.x * 64, bh = blockIdx.y, b = bh >> 4, h = bh & 15;
#pragma unroll
    for (int it = 0; it < 2; ++it) {
        int idx = it * 2048 + tid * 8;
        int r = idx >> 6, e0 = idx & 63;
        bf16x8 val = *(const bf16x8*)(vh + ((size_t)b * 2048 + s0 + r) * 1024 + h * 64 + e0);
#pragma unroll
        for (int j = 0; j < 8; ++j) T[r][e0 + j] = val[j];
    }
    __syncthreads();
#pragma unroll
    for (int u0 = 0; u0 < 2; ++u0) {
        int u = u0 * 256 + tid;            // chunk 0..511: [mt][kk][hi][e31]
        int mt = u >> 8, rem = u & 255;
        int kk = rem >> 6, hi = (rem >> 5) & 1, e31 = rem & 31;
        bf16x8 o;
#pragma unroll
        for (int j = 0; j < 8; ++j) o[j] = T[kk * 16 + hi * 8 + j][mt * 32 + e31];
        *(bf16x8*)(Vp + ((size_t)bh * 32 + blockIdx.x) * 4096 + u * 8) = o;
    }
}

// ---------------- fused QKV GEMM (grid: x=m 32, y=n 8, z=3; XCD = m%8) ------
__global__ __launch_bounds__(256) void gemm_qkv(
    const __bf16* __restrict__ qb, const __bf16* __restrict__ kb,
    const __bf16* __restrict__ vb, const __bf16* __restrict__ w3,
    const float* __restrict__ bq, const float* __restrict__ bk,
    const float* __restrict__ bv,
    __bf16* __restrict__ qo, __bf16* __restrict__ ko, __bf16* __restrict__ vo) {
    __shared__ __bf16 As[128 * 64];
    __shared__ __bf16 Bs[128 * 64];
    int z = blockIdx.z;
    const __bf16* A = z == 0 ? qb : (z == 1 ? kb : vb);
    const __bf16* Bt = w3 + ((size_t)z << 20);
    const float* bias = z == 0 ? bq : (z == 1 ? bk : bv);
    __bf16* dst = z == 0 ? qo : (z == 1 ? ko : vo);
    float sc = z == 0 ? QSCL : 1.0f;

    int tid = threadIdx.x;
    int w = tid >> 6, lane = tid & 63, lg = lane >> 4, lr = lane & 15;
    int wr = (w >> 1) * 64, wc = (w & 1) * 64;
    int m0 = blockIdx.x * 128, n0 = blockIdx.y * 128;   // m fastest -> XCD=m%8
    f32x4 acc[4][4] = {};
    for (int k0 = 0; k0 < 1024; k0 += 64) {
        __syncthreads();
        stage_tile<128>(A + (size_t)m0 * 1024 + k0, 1024, As, tid);
        stage_tile<128>(Bt + (size_t)n0 * 1024 + k0, 1024, Bs, tid);
        __syncthreads();
#pragma unroll
        for (int kk = 0; kk < 2; ++kk) {
            bf16x8 af[4], bfr[4];
#pragma unroll
            for (int t = 0; t < 4; ++t) {
                af[t] = lds_frag(As, wr + t * 16 + lr, lg * 16 + kk * 64);
                bfr[t] = lds_frag(Bs, wc + t * 16 + lr, lg * 16 + kk * 64);
            }
#pragma unroll
            for (int i = 0; i < 4; ++i)
#pragma unroll
                for (int j = 0; j < 4; ++j)
                    acc[i][j] = __builtin_amdgcn_mfma_f32_16x16x32_bf16(
                        af[i], bfr[j], acc[i][j], 0, 0, 0);
        }
    }
#pragma unroll
    for (int i = 0; i < 4; ++i) {
        int mb = m0 + wr + i * 16 + lg * 4;
#pragma unroll
        for (int j = 0; j < 4; ++j) {
            int n = n0 + wc + j * 16 + lr;
            float bvv = bias[n];
#pragma unroll
            for (int r = 0; r < 4; ++r)
                dst[(size_t)(mb + r) * 1024 + n] = (__bf16)((acc[i][j][r] + bvv) * sc);
        }
    }
}

// ---------------- final GEMM + GELU (grid: x=m 64, y=n 8; XCD = m%8) --------
__global__ __launch_bounds__(256) void gemm_out(const __bf16* __restrict__ A,
                                                const __bf16* __restrict__ Bt,
                                                const float* __restrict__ bias,
                                                float* __restrict__ dst) {
    __shared__ __bf16 As[64 * 64];
    __shared__ __bf16 Bs[128 * 64];
    int tid = threadIdx.x;
    int w = tid >> 6, lane = tid & 63, lg = lane >> 4, lr = lane & 15;
    int wr = (w >> 1) * 32, wc = (w & 1) * 64;
    int m0 = blockIdx.x * 64, n0 = blockIdx.y * 128;    // m fastest -> XCD=m%8
    f32x4 acc[2][4] = {};
    for (int k0 = 0; k0 < 1024; k0 += 64) {
        __syncthreads();
        stage_tile<64>(A + (size_t)m0 * 1024 + k0, 1024, As, tid);
        stage_tile<128>(Bt + (size_t)n0 * 1024 + k0, 1024, Bs, tid);
        __syncthreads();
#pragma unroll
        for (int kk = 0; kk < 2; ++kk) {
            bf16x8 af[2], bfr[4];
#pragma unroll
            for (int t = 0; t < 2; ++t)
                af[t] = lds_frag(As, wr + t * 16 + lr, lg * 16 + kk * 64);
#pragma unroll
            for (int t = 0; t < 4; ++t)
                bfr[t] = lds_frag(Bs, wc + t * 16 + lr, lg * 16 + kk * 64);
#pragma unroll
            for (int i = 0; i < 2; ++i)
#pragma unroll
                for (int j = 0; j < 4; ++j)
                    acc[i][j] = __builtin_amdgcn_mfma_f32_16x16x32_bf16(
                        af[i], bfr[j], acc[i][j], 0, 0, 0);
        }
    }
#pragma unroll
    for (int i = 0; i < 2; ++i) {
        int mb = m0 + wr + i * 16 + lg * 4;
#pragma unroll
        for (int j = 0; j < 4; ++j) {
            int n = n0 + wc + j * 16 + lr;
            float bvv = bias[n];
#pragma unroll
            for (int r = 0; r < 4; ++r) {
                float v = acc[i][j][r] + bvv;
                float g = v / (1.f + exp2f(GELC * v));
                dst[(size_t)(mb + r) * 1024 + n] = g;
            }
        }
    }
}

// ---------------- flash attention: LDS-free, fragment-packed streams --------
// 1D grid 1024, XCD decode as R9. 4 independent waves (no barriers, no LDS):
// wave = 32 q-rows, kv half [z*1024,+1024) in 16 64-tiles. All K/V/Q frags are
// coalesced 1KB global loads from packed buffers; K prefetched 1 tile ahead;
// V loads issued before exp2 (latency hides under transcendental block).
__global__ __launch_bounds__(256) void attn_kernel(
    const __bf16* __restrict__ Qp, const __bf16* __restrict__ Kp,
    const __bf16* __restrict__ Vp, const float* __restrict__ mask,
    const unsigned* __restrict__ flags,
    __bf16* __restrict__ Op0, __bf16* __restrict__ Op1,
    float* __restrict__ lacc) {
    int tid = threadIdx.x;
    int w = tid >> 6, l = tid & 63;
    int q31 = l & 31, hi = l >> 5;
    int i = blockIdx.x;
    int xcd = i & 7, j = i >> 3;
    int group = (j >> 4) * 8 + xcd;
    int qt = j & 15;
    int bh = group & 31, z = group >> 5;
    int b = bh >> 4, h = bh & 15;
    int qw = qt * 128 + w * 32;

    // Q frags: per (b,h) block sb = qw/32; lane offset kk*512 + l*8
    const __bf16* Qb = Qp + ((size_t)bh * 64 + (qw >> 5)) * 2048 + l * 8;
    bf16x8 qf[4];
#pragma unroll
    for (int kk = 0; kk < 4; ++kk) qf[kk] = *(const bf16x8*)(Qb + kk * 512);

    const __bf16* Kb = Kp + ((size_t)bh * 64 + z * 32) * 2048 + l * 8;
    const __bf16* Vb = Vp + ((size_t)bh * 32 + z * 16) * 4096 + l * 8;
    const float* mrow = mask + (size_t)b * 4194304 + (size_t)(qw + q31) * 2048 + (z << 10) + hi * 4;
    const unsigned* flg = flags + (b * 16 + qt) * 32 + z * 16;

    f32x16 O[2] = {};
    float l_acc = 0.f;

    // K prefetch tile 0: sb = kt*2 + mt, frag at sb*2048 + kk*512
    bf16x8 kf[2][4];
#pragma unroll
    for (int mt = 0; mt < 2; ++mt)
#pragma unroll
        for (int kk = 0; kk < 4; ++kk)
            kf[mt][kk] = *(const bf16x8*)(Kb + (mt * 4 + kk) * 512);

    for (int kt = 0; kt < 16; ++kt) {
        f32x16 T[2] = {};
        __builtin_amdgcn_s_setprio(1);
#pragma unroll
        for (int kk = 0; kk < 4; ++kk)
#pragma unroll
            for (int mt = 0; mt < 2; ++mt)
                T[mt] = __builtin_amdgcn_mfma_f32_32x32x16_bf16(kf[mt][kk], qf[kk], T[mt], 0, 0, 0);
        __builtin_amdgcn_s_setprio(0);

        // V loads for this tile + K prefetch for next: in flight across exp2
        bf16x8 vf[2][4];
#pragma unroll
        for (int mt = 0; mt < 2; ++mt)
#pragma unroll
            for (int kk = 0; kk < 4; ++kk)
                vf[mt][kk] = *(const bf16x8*)(Vb + (size_t)kt * 4096 + (mt * 4 + kk) * 512);
        if (kt < 15) {
#pragma unroll
            for (int mt = 0; mt < 2; ++mt)
#pragma unroll
                for (int kk = 0; kk < 4; ++kk)
                    kf[mt][kk] = *(const bf16x8*)(Kb + ((size_t)(kt + 1) * 2 + mt) * 2048 + kk * 512);
        }

        // flag-gated mask add (wave-uniform branch), then max-free exp2
        unsigned fl = __builtin_amdgcn_readfirstlane(flg[kt]);
        if (fl) {
#pragma unroll
            for (int mt = 0; mt < 2; ++mt)
#pragma unroll
                for (int g = 0; g < 4; ++g) {
                    f32x4 mk = *(const f32x4*)(mrow + kt * 64 + mt * 32 + g * 8);
#pragma unroll
                    for (int c = 0; c < 4; ++c)
                        T[mt][4 * g + c] = fmaf(mk[c], L2E, T[mt][4 * g + c]);
                }
        }
#pragma unroll
        for (int mt = 0; mt < 2; ++mt)
#pragma unroll
            for (int g = 0; g < 4; ++g) {
                float p0 = exp2f(T[mt][4 * g + 0]);
                float p1 = exp2f(T[mt][4 * g + 1]);
                float p2 = exp2f(T[mt][4 * g + 2]);
                float p3 = exp2f(T[mt][4 * g + 3]);
                l_acc += (p0 + p1) + (p2 + p3);
                T[mt][4 * g + 0] = p0; T[mt][4 * g + 1] = p1;
                T[mt][4 * g + 2] = p2; T[mt][4 * g + 3] = p3;
            }

        // P frags in-register: pf[kk][j] = P[q=q31][kv = kk*16 + hi*8 + j]
        bf16x8 pf[4];
#pragma unroll
        for (int kk = 0; kk < 4; ++kk) {
            int mt = kk >> 1;
            int gA = (2 * kk) & 3, gB = gA + 1;
            unsigned x0 = cvtpk(T[mt][4 * gA + 0], T[mt][4 * gA + 1]);
            unsigned x1 = cvtpk(T[mt][4 * gA + 2], T[mt][4 * gA + 3]);
            unsigned y0 = cvtpk(T[mt][4 * gB + 0], T[mt][4 * gB + 1]);
            unsigned y1 = cvtpk(T[mt][4 * gB + 2], T[mt][4 * gB + 3]);
            pswap(x0, y0);
            pswap(x1, y1);
            u32x4 packed; packed[0] = x0; packed[1] = x1; packed[2] = y0; packed[3] = y1;
            pf[kk] = __builtin_bit_cast(bf16x8, packed);
        }

        __builtin_amdgcn_s_setprio(1);
#pragma unroll
        for (int kk = 0; kk < 4; ++kk)
#pragma unroll
            for (int mt = 0; mt < 2; ++mt)
                O[mt] = __builtin_amdgcn_mfma_f32_32x32x16_bf16(vf[mt][kk], pf[kk], O[mt], 0, 0, 0);
        __builtin_amdgcn_s_setprio(0);
    }

    // combine via plain coalesced stores (one writer per address)
    l_acc += __shfl_xor(l_acc, 32, 64);
    if (hi == 0)
        lacc[((size_t)z * 32 + b * 16 + h) * 2048 + qw + q31] = l_acc;
    __bf16* Ob = (z ? Op1 : Op0) + (((size_t)(b * 16 + h)) * 2048 + qw + q31) * 64 + hi * 4;
#pragma unroll
    for (int mt = 0; mt < 2; ++mt)
#pragma unroll
        for (int g = 0; g < 4; ++g) {
            bf16x4 o;
#pragma unroll
            for (int c = 0; c < 4; ++c) o[c] = (__bf16)O[mt][4 * g + c];
            *(bf16x4*)(Ob + mt * 32 + g * 8) = o;
        }
}

// normalize: x[b,s,h*64+e] = bf16((Op0+Op1)[b][h][s][e] / (l0+l1)[b][h][s])
__global__ __launch_bounds__(256) void attn_norm(const __bf16* __restrict__ Op0,
                                                 const __bf16* __restrict__ Op1,
                                                 const float* __restrict__ lacc,
                                                 __bf16* __restrict__ x) {
    int idx = blockIdx.x * 256 + threadIdx.x;   // 1,048,576 total
    int b = idx >> 19;
    int rem = idx & 524287;                     // h[4] s[11] e4[4]
    int h = rem >> 15;
    int s = (rem >> 4) & 2047;
    int e0 = (rem & 15) * 4;
    size_t base = (((size_t)(b * 16 + h)) * 2048 + s) * 64 + e0;
    bf16x4 a = *(const bf16x4*)(Op0 + base);
    bf16x4 c = *(const bf16x4*)(Op1 + base);
    size_t li = ((size_t)(b * 16 + h)) * 2048 + s;
    float inv = 1.0f / (lacc[li] + lacc[65536 + li]);
    bf16x4 r;
#pragma unroll
    for (int j = 0; j < 4; ++j)
        r[j] = (__bf16)(((float)a[j] + (float)c[j]) * inv);
    *(bf16x4*)(x + ((size_t)b * 2048 + s) * 1024 + h * 64 + e0) = r;
}

// ---------------- launch ----------------

extern "C" void kernel_launch(void* const* d_in, const int* in_sizes, int n_in,
                              void* d_out, int out_size, void* d_ws, size_t ws_size,
                              hipStream_t stream) {
    const float* q    = (const float*)d_in[0];
    const float* k    = (const float*)d_in[1];
    const float* v    = (const float*)d_in[2];
    const float* mask = (const float*)d_in[3];
    const float* Wq   = (const float*)d_in[4];
    const float* bq   = (const float*)d_in[5];
    const float* Wk   = (const float*)d_in[6];
    const float* bk   = (const float*)d_in[7];
    const float* Wv   = (const float*)d_in[8];
    const float* bv   = (const float*)d_in[9];
    const float* Wo   = (const float*)d_in[10];
    const float* bo   = (const float*)d_in[11];

    char* ws = (char*)d_ws;
    __bf16* qb  = (__bf16*)(ws + (0ull  << 20));   // -> Qp (after qkpack)
    __bf16* kb  = (__bf16*)(ws + (8ull  << 20));   // -> Vp (after vpack)
    __bf16* vb  = (__bf16*)(ws + (16ull << 20));   // -> Kp (after qkpack)
    __bf16* w3  = (__bf16*)(ws + (24ull << 20));   // 6 MB
    __bf16* wo  = (__bf16*)(ws + (30ull << 20));   // 2 MB (live till end)
    __bf16* qhp = (__bf16*)(ws + (32ull << 20));   // -> Op0 (after qkpack)
    __bf16* khp = (__bf16*)(ws + (40ull << 20));   // -> Op1 (after qkpack)
    __bf16* vhp = (__bf16*)(ws + (48ull << 20));   // -> x   (after vpack)
    float*  laccp = (float*)(ws + (56ull << 20));                        // 512 KB
    unsigned* flagp = (unsigned*)(ws + (56ull << 20) + (512ull << 10));  // 4 KB
    __bf16* Qpk = qb;
    __bf16* Vpk = kb;
    __bf16* Kpk = vb;
    __bf16* Op0 = qhp;
    __bf16* Op1 = khp;
    __bf16* xp  = vhp;

    cvt3_kernel<<<dim3(4096, 3), 256, 0, stream>>>(q, k, v, qb, kb, vb);
    pack_wqkv<<<dim3(16, 16, 3), 256, 0, stream>>>(Wq, Wk, Wv, w3);
    pack_wo<<<dim3(16, 16), 256, 0, stream>>>(Wo, wo);
    flags_init<<<1, 256, 0, stream>>>(flagp);
    mask_flags<<<8192, 256, 0, stream>>>(mask, flagp);

    gemm_qkv<<<dim3(32, 8, 3), 256, 0, stream>>>(qb, kb, vb, w3, bq, bk, bv,
                                                 qhp, khp, vhp);
    qkpack<<<dim3(32, 32, 2), 256, 0, stream>>>(qhp, khp, Qpk, Kpk);
    vpack<<<dim3(32, 32), 256, 0, stream>>>(vhp, Vpk);

    attn_kernel<<<dim3(1024), 256, 0, stream>>>(Qpk, Kpk, Vpk, mask, flagp,
                                                Op0, Op1, laccp);
    attn_norm<<<4096, 256, 0, stream>>>(Op0, Op1, laccp, xp);

    gemm_out<<<dim3(64, 8), 256, 0, stream>>>(xp, wo, bo, (float*)d_out);
}

// Round 11
// 156.964 us; speedup vs baseline: 2.4803x; 1.0556x over previous
//
#include <hip/hip_runtime.h>
#include <stdint.h>

// MultiHeadedAttention: B=2,S=2048,D=1024,H=16,HD=64
// R11 = R10 with packing FUSED into gemm_qkv's epilogue (qkpack/vpack deleted):
// gemm_qkv writes Q/K directly in [sb32][kk][hi][q31][8] fragment order and V
// in [kv64][mt][kk][hi][e31][8] (V epilogue is bf16x4-contiguous -> better
// than old row-major). flags_init replaced by hipMemsetAsync. attn identical
// to R10 except l_acc split into 2 accumulators (shorter dep chain).
// Workspace map (MB): 0-8 qb->Op0, 8-16 kb->Op1, 16-24 vb->x, 24-30 w3,
// 30-32 wo, 32-40 Qp, 40-48 Kp, 48-56 Vp, 56+ lacc(512KB)+flags(4KB)

typedef __bf16 bf16x8 __attribute__((ext_vector_type(8)));
typedef __bf16 bf16x4 __attribute__((ext_vector_type(4)));
typedef float f32x4 __attribute__((ext_vector_type(4)));
typedef float f32x16 __attribute__((ext_vector_type(16)));
typedef unsigned u32x4 __attribute__((ext_vector_type(4)));

static constexpr float L2E  = 1.4426950408889634f;
static constexpr float QSCL = 0.18033688011112042f;   // 0.125 * log2(e)
static constexpr float GELC = -2.4554669595930157f;   // -1.702 * log2(e)

__device__ __forceinline__ void async_load16(const void* g, void* l) {
    __builtin_amdgcn_global_load_lds(
        (const __attribute__((address_space(1))) unsigned int*)(uintptr_t)g,
        (__attribute__((address_space(3))) unsigned int*)(unsigned int)(uintptr_t)l,
        16, 0, 0);
}

// Stage ROWS x 64-bf16 tile into LDS, phys = row*128 + (kb ^ ((row&7)<<4)).
template <int ROWS>
__device__ __forceinline__ void stage_tile(const __bf16* g, int ld, __bf16* lds, int tid) {
#pragma unroll
    for (int r = 0; r < ROWS / 32; ++r) {
        int p = r * 4096 + tid * 16;
        int row = p >> 7;
        int kbp = p & 127;
        int kbl = kbp ^ ((row & 7) << 4);
        async_load16((const char*)(g + (size_t)row * ld) + kbl,
                     (char*)lds + (p & ~1023));
    }
}

__device__ __forceinline__ bf16x8 lds_frag(const __bf16* base, int row, int kb) {
    return *(const bf16x8*)((const char*)base + (row << 7) + (kb ^ ((row & 7) << 4)));
}

__device__ __forceinline__ unsigned cvtpk(float a, float b) {
    unsigned d;
    asm("v_cvt_pk_bf16_f32 %0, %1, %2" : "=v"(d) : "v"(a), "v"(b));
    return d;
}
__device__ __forceinline__ void pswap(unsigned& a, unsigned& b) {
    asm("v_permlane32_swap_b32 %0, %1" : "+v"(a), "+v"(b));
}

// ---------------- prep kernels ----------------

__global__ __launch_bounds__(256) void cvt3_kernel(const float* __restrict__ q,
                                                   const float* __restrict__ k,
                                                   const float* __restrict__ v,
                                                   __bf16* __restrict__ qb,
                                                   __bf16* __restrict__ kb,
                                                   __bf16* __restrict__ vb) {
    int z = blockIdx.y;
    const float* src = z == 0 ? q : (z == 1 ? k : v);
    __bf16* dst = z == 0 ? qb : (z == 1 ? kb : vb);
    int i = blockIdx.x * 256 + threadIdx.x;
    f32x4 val = ((const f32x4*)src)[i];
    bf16x4 o;
    o[0] = (__bf16)val[0]; o[1] = (__bf16)val[1];
    o[2] = (__bf16)val[2]; o[3] = (__bf16)val[3];
    ((bf16x4*)dst)[i] = o;
}

// Per-(b, q/128, kv/64) nonzero flags from the f32 mask (zero mask => 0 atomics)
__global__ __launch_bounds__(256) void mask_flags(const float* __restrict__ m,
                                                  unsigned* __restrict__ flags) {
    int i = blockIdx.x * 256 + threadIdx.x;    // over B*S*S/4 = 2,097,152
    f32x4 v = ((const f32x4*)m)[i];
    bool nz = (v[0] != 0.f) | (v[1] != 0.f) | (v[2] != 0.f) | (v[3] != 0.f);
    if (nz) {
        size_t i4 = (size_t)i * 4;
        int b = (int)(i4 >> 22);
        int rem = (int)(i4 & 4194303);
        int qq = rem >> 11, kv = rem & 2047;
        atomicOr(flags + (b * 16 + (qq >> 7)) * 32 + (kv >> 6), 1u);
    }
}

__global__ __launch_bounds__(256) void pack_wqkv(const float* __restrict__ Wq,
                                                 const float* __restrict__ Wk,
                                                 const float* __restrict__ Wv,
                                                 __bf16* __restrict__ out) {
    __shared__ __bf16 T[64][72];
    int tid = threadIdx.x;
    int k0 = blockIdx.x * 64, h = blockIdx.y, z = blockIdx.z;
    const float* W = z == 0 ? Wq : (z == 1 ? Wk : Wv);
#pragma unroll
    for (int it = 0; it < 4; ++it) {
        int idx = it * 1024 + tid * 4;
        int r = idx >> 6, e = idx & 63;
        f32x4 val = *(const f32x4*)(W + ((size_t)h * 1024 + k0 + r) * 64 + e);
#pragma unroll
        for (int j = 0; j < 4; ++j) T[r][e + j] = (__bf16)val[j];
    }
    __syncthreads();
    int e2 = tid >> 2, kc = (tid & 3) * 16;
    bf16x8 o0, o1;
#pragma unroll
    for (int i = 0; i < 8; ++i) { o0[i] = T[kc + i][e2]; o1[i] = T[kc + 8 + i][e2]; }
    __bf16* dst = out + ((size_t)z << 20) + (size_t)(h * 64 + e2) * 1024 + k0 + kc;
    *(bf16x8*)dst = o0;
    *(bf16x8*)(dst + 8) = o1;
}

__global__ __launch_bounds__(256) void pack_wo(const float* __restrict__ Wo,
                                               __bf16* __restrict__ out) {
    __shared__ __bf16 T[64][72];
    int tid = threadIdx.x;
    int k0 = blockIdx.x * 64, n0 = blockIdx.y * 64;
#pragma unroll
    for (int it = 0; it < 4; ++it) {
        int idx = it * 1024 + tid * 4;
        int r = idx >> 6, e = idx & 63;
        f32x4 val = *(const f32x4*)(Wo + (size_t)(k0 + r) * 1024 + n0 + e);
#pragma unroll
        for (int j = 0; j < 4; ++j) T[r][e + j] = (__bf16)val[j];
    }
    __syncthreads();
    int e2 = tid >> 2, kc = (tid & 3) * 16;
    bf16x8 o0, o1;
#pragma unroll
    for (int i = 0; i < 8; ++i) { o0[i] = T[kc + i][e2]; o1[i] = T[kc + 8 + i][e2]; }
    __bf16* dst = out + (size_t)(n0 + e2) * 1024 + k0 + kc;
    *(bf16x8*)dst = o0;
    *(bf16x8*)(dst + 8) = o1;
}

// ---------------- fused QKV GEMM + fragment-pack epilogue -------------------
// grid (x=m 32, y=n 8, z=3; XCD = m%8).
// z=0/1: write Q/K packed per (b,h): [s/32][kk][hi][q31][8]
// z=2:   write V packed per (b,h): [s/64][mt][kk][hi][e31][8] (bf16x4 stores)
__global__ __launch_bounds__(256) void gemm_qkv(
    const __bf16* __restrict__ qb, const __bf16* __restrict__ kb,
    const __bf16* __restrict__ vb, const __bf16* __restrict__ w3,
    const float* __restrict__ bq, const float* __restrict__ bk,
    const float* __restrict__ bv,
    __bf16* __restrict__ Qp, __bf16* __restrict__ Kp, __bf16* __restrict__ Vp) {
    __shared__ __bf16 As[128 * 64];
    __shared__ __bf16 Bs[128 * 64];
    int z = blockIdx.z;
    const __bf16* A = z == 0 ? qb : (z == 1 ? kb : vb);
    const __bf16* Bt = w3 + ((size_t)z << 20);
    const float* bias = z == 0 ? bq : (z == 1 ? bk : bv);
    float sc = z == 0 ? QSCL : 1.0f;

    int tid = threadIdx.x;
    int w = tid >> 6, lane = tid & 63, lg = lane >> 4, lr = lane & 15;
    int wr = (w >> 1) * 64, wc = (w & 1) * 64;
    int m0 = blockIdx.x * 128, n0 = blockIdx.y * 128;   // m fastest -> XCD=m%8
    f32x4 acc[4][4] = {};
    for (int k0 = 0; k0 < 1024; k0 += 64) {
        __syncthreads();
        stage_tile<128>(A + (size_t)m0 * 1024 + k0, 1024, As, tid);
        stage_tile<128>(Bt + (size_t)n0 * 1024 + k0, 1024, Bs, tid);
        __syncthreads();
#pragma unroll
        for (int kk = 0; kk < 2; ++kk) {
            bf16x8 af[4], bfr[4];
#pragma unroll
            for (int t = 0; t < 4; ++t) {
                af[t] = lds_frag(As, wr + t * 16 + lr, lg * 16 + kk * 64);
                bfr[t] = lds_frag(Bs, wc + t * 16 + lr, lg * 16 + kk * 64);
            }
#pragma unroll
            for (int i = 0; i < 4; ++i)
#pragma unroll
                for (int j = 0; j < 4; ++j)
                    acc[i][j] = __builtin_amdgcn_mfma_f32_16x16x32_bf16(
                        af[i], bfr[j], acc[i][j], 0, 0, 0);
        }
    }
#pragma unroll
    for (int i = 0; i < 4; ++i) {
        int mb = m0 + wr + i * 16 + lg * 4;
        int b = mb >> 11, s = mb & 2047;
#pragma unroll
        for (int j = 0; j < 4; ++j) {
            int n = n0 + wc + j * 16 + lr;
            float bvv = bias[n];
            int h = n >> 6, e = n & 63;
            int bh = b * 16 + h;
            if (z == 2) {
                // packed V: contiguous over s&7 -> one bf16x4 store
                size_t addr = ((size_t)bh * 32 + (s >> 6)) * 4096 + (e >> 5) * 2048 +
                              ((s >> 4) & 3) * 512 + ((s >> 3) & 1) * 256 +
                              (e & 31) * 8 + (s & 7);
                bf16x4 o;
#pragma unroll
                for (int r = 0; r < 4; ++r) o[r] = (__bf16)(acc[i][j][r] + bvv);
                *(bf16x4*)(Vp + addr) = o;
            } else {
                __bf16* out = z == 0 ? Qp : Kp;
                size_t base = ((size_t)bh * 64 + (s >> 5)) * 2048 + (e >> 4) * 512 +
                              ((e >> 3) & 1) * 256 + (s & 31) * 8 + (e & 7);
#pragma unroll
                for (int r = 0; r < 4; ++r)
                    out[base + r * 8] = (__bf16)((acc[i][j][r] + bvv) * sc);
            }
        }
    }
}

// ---------------- final GEMM + GELU (grid: x=m 64, y=n 8; XCD = m%8) --------
__global__ __launch_bounds__(256) void gemm_out(const __bf16* __restrict__ A,
                                                const __bf16* __restrict__ Bt,
                                                const float* __restrict__ bias,
                                                float* __restrict__ dst) {
    __shared__ __bf16 As[64 * 64];
    __shared__ __bf16 Bs[128 * 64];
    int tid = threadIdx.x;
    int w = tid >> 6, lane = tid & 63, lg = lane >> 4, lr = lane & 15;
    int wr = (w >> 1) * 32, wc = (w & 1) * 64;
    int m0 = blockIdx.x * 64, n0 = blockIdx.y * 128;    // m fastest -> XCD=m%8
    f32x4 acc[2][4] = {};
    for (int k0 = 0; k0 < 1024; k0 += 64) {
        __syncthreads();
        stage_tile<64>(A + (size_t)m0 * 1024 + k0, 1024, As, tid);
        stage_tile<128>(Bt + (size_t)n0 * 1024 + k0, 1024, Bs, tid);
        __syncthreads();
#pragma unroll
        for (int kk = 0; kk < 2; ++kk) {
            bf16x8 af[2], bfr[4];
#pragma unroll
            for (int t = 0; t < 2; ++t)
                af[t] = lds_frag(As, wr + t * 16 + lr, lg * 16 + kk * 64);
#pragma unroll
            for (int t = 0; t < 4; ++t)
                bfr[t] = lds_frag(Bs, wc + t * 16 + lr, lg * 16 + kk * 64);
#pragma unroll
            for (int i = 0; i < 2; ++i)
#pragma unroll
                for (int j = 0; j < 4; ++j)
                    acc[i][j] = __builtin_amdgcn_mfma_f32_16x16x32_bf16(
                        af[i], bfr[j], acc[i][j], 0, 0, 0);
        }
    }
#pragma unroll
    for (int i = 0; i < 2; ++i) {
        int mb = m0 + wr + i * 16 + lg * 4;
#pragma unroll
        for (int j = 0; j < 4; ++j) {
            int n = n0 + wc + j * 16 + lr;
            float bvv = bias[n];
#pragma unroll
            for (int r = 0; r < 4; ++r) {
                float v = acc[i][j][r] + bvv;
                float g = v / (1.f + exp2f(GELC * v));
                dst[(size_t)(mb + r) * 1024 + n] = g;
            }
        }
    }
}

// ---------------- flash attention: LDS-free, fragment-packed streams --------
// 1D grid 1024, XCD decode as R9/R10. No barriers, no LDS. K reg-prefetched
// one tile ahead; V loads issued before exp2 block. l accumulated in 2
// mt-partials (shorter dependency chain).
__global__ __launch_bounds__(256) void attn_kernel(
    const __bf16* __restrict__ Qp, const __bf16* __restrict__ Kp,
    const __bf16* __restrict__ Vp, const float* __restrict__ mask,
    const unsigned* __restrict__ flags,
    __bf16* __restrict__ Op0, __bf16* __restrict__ Op1,
    float* __restrict__ lacc) {
    int tid = threadIdx.x;
    int w = tid >> 6, l = tid & 63;
    int q31 = l & 31, hi = l >> 5;
    int i = blockIdx.x;
    int xcd = i & 7, j = i >> 3;
    int group = (j >> 4) * 8 + xcd;
    int qt = j & 15;
    int bh = group & 31, z = group >> 5;
    int b = bh >> 4, h = bh & 15;
    int qw = qt * 128 + w * 32;

    // Q frags: per (b,h) block sb = qw/32; lane offset kk*512 + l*8
    const __bf16* Qb = Qp + ((size_t)bh * 64 + (qw >> 5)) * 2048 + l * 8;
    bf16x8 qf[4];
#pragma unroll
    for (int kk = 0; kk < 4; ++kk) qf[kk] = *(const bf16x8*)(Qb + kk * 512);

    const __bf16* Kb = Kp + ((size_t)bh * 64 + z * 32) * 2048 + l * 8;
    const __bf16* Vb = Vp + ((size_t)bh * 32 + z * 16) * 4096 + l * 8;
    const float* mrow = mask + (size_t)b * 4194304 + (size_t)(qw + q31) * 2048 + (z << 10) + hi * 4;
    const unsigned* flg = flags + (b * 16 + qt) * 32 + z * 16;

    f32x16 O[2] = {};
    float la0 = 0.f, la1 = 0.f;

    // K prefetch tile 0: sb = kt*2 + mt, frag at sb*2048 + kk*512
    bf16x8 kf[2][4];
#pragma unroll
    for (int mt = 0; mt < 2; ++mt)
#pragma unroll
        for (int kk = 0; kk < 4; ++kk)
            kf[mt][kk] = *(const bf16x8*)(Kb + (mt * 4 + kk) * 512);

    for (int kt = 0; kt < 16; ++kt) {
        f32x16 T[2] = {};
        __builtin_amdgcn_s_setprio(1);
#pragma unroll
        for (int kk = 0; kk < 4; ++kk)
#pragma unroll
            for (int mt = 0; mt < 2; ++mt)
                T[mt] = __builtin_amdgcn_mfma_f32_32x32x16_bf16(kf[mt][kk], qf[kk], T[mt], 0, 0, 0);
        __builtin_amdgcn_s_setprio(0);

        // V loads for this tile + K prefetch for next: in flight across exp2
        bf16x8 vf[2][4];
#pragma unroll
        for (int mt = 0; mt < 2; ++mt)
#pragma unroll
            for (int kk = 0; kk < 4; ++kk)
                vf[mt][kk] = *(const bf16x8*)(Vb + (size_t)kt * 4096 + (mt * 4 + kk) * 512);
        if (kt < 15) {
#pragma unroll
            for (int mt = 0; mt < 2; ++mt)
#pragma unroll
                for (int kk = 0; kk < 4; ++kk)
                    kf[mt][kk] = *(const bf16x8*)(Kb + ((size_t)(kt + 1) * 2 + mt) * 2048 + kk * 512);
        }

        // flag-gated mask add (wave-uniform branch), then max-free exp2
        unsigned fl = __builtin_amdgcn_readfirstlane(flg[kt]);
        if (fl) {
#pragma unroll
            for (int mt = 0; mt < 2; ++mt)
#pragma unroll
                for (int g = 0; g < 4; ++g) {
                    f32x4 mk = *(const f32x4*)(mrow + kt * 64 + mt * 32 + g * 8);
#pragma unroll
                    for (int c = 0; c < 4; ++c)
                        T[mt][4 * g + c] = fmaf(mk[c], L2E, T[mt][4 * g + c]);
                }
        }
#pragma unroll
        for (int g = 0; g < 4; ++g) {
            float a0 = exp2f(T[0][4 * g + 0]);
            float a1 = exp2f(T[0][4 * g + 1]);
            float a2 = exp2f(T[0][4 * g + 2]);
            float a3 = exp2f(T[0][4 * g + 3]);
            float b0 = exp2f(T[1][4 * g + 0]);
            float b1 = exp2f(T[1][4 * g + 1]);
            float b2 = exp2f(T[1][4 * g + 2]);
            float b3 = exp2f(T[1][4 * g + 3]);
            la0 += (a0 + a1) + (a2 + a3);
            la1 += (b0 + b1) + (b2 + b3);
            T[0][4 * g + 0] = a0; T[0][4 * g + 1] = a1;
            T[0][4 * g + 2] = a2; T[0][4 * g + 3] = a3;
            T[1][4 * g + 0] = b0; T[1][4 * g + 1] = b1;
            T[1][4 * g + 2] = b2; T[1][4 * g + 3] = b3;
        }

        // P frags in-register: pf[kk][j] = P[q=q31][kv = kk*16 + hi*8 + j]
        bf16x8 pf[4];
#pragma unroll
        for (int kk = 0; kk < 4; ++kk) {
            int mt = kk >> 1;
            int gA = (2 * kk) & 3, gB = gA + 1;
            unsigned x0 = cvtpk(T[mt][4 * gA + 0], T[mt][4 * gA + 1]);
            unsigned x1 = cvtpk(T[mt][4 * gA + 2], T[mt][4 * gA + 3]);
            unsigned y0 = cvtpk(T[mt][4 * gB + 0], T[mt][4 * gB + 1]);
            unsigned y1 = cvtpk(T[mt][4 * gB + 2], T[mt][4 * gB + 3]);
            pswap(x0, y0);
            pswap(x1, y1);
            u32x4 packed; packed[0] = x0; packed[1] = x1; packed[2] = y0; packed[3] = y1;
            pf[kk] = __builtin_bit_cast(bf16x8, packed);
        }

        __builtin_amdgcn_s_setprio(1);
#pragma unroll
        for (int kk = 0; kk < 4; ++kk)
#pragma unroll
            for (int mt = 0; mt < 2; ++mt)
                O[mt] = __builtin_amdgcn_mfma_f32_32x32x16_bf16(vf[mt][kk], pf[kk], O[mt], 0, 0, 0);
        __builtin_amdgcn_s_setprio(0);
    }

    // combine via plain coalesced stores (one writer per address)
    float l_acc = la0 + la1;
    l_acc += __shfl_xor(l_acc, 32, 64);
    if (hi == 0)
        lacc[((size_t)z * 32 + b * 16 + h) * 2048 + qw + q31] = l_acc;
    __bf16* Ob = (z ? Op1 : Op0) + (((size_t)(b * 16 + h)) * 2048 + qw + q31) * 64 + hi * 4;
#pragma unroll
    for (int mt = 0; mt < 2; ++mt)
#pragma unroll
        for (int g = 0; g < 4; ++g) {
            bf16x4 o;
#pragma unroll
            for (int c = 0; c < 4; ++c) o[c] = (__bf16)O[mt][4 * g + c];
            *(bf16x4*)(Ob + mt * 32 + g * 8) = o;
        }
}

// normalize: x[b,s,h*64+e] = bf16((Op0+Op1)[b][h][s][e] / (l0+l1)[b][h][s])
__global__ __launch_bounds__(256) void attn_norm(const __bf16* __restrict__ Op0,
                                                 const __bf16* __restrict__ Op1,
                                                 const float* __restrict__ lacc,
                                                 __bf16* __restrict__ x) {
    int idx = blockIdx.x * 256 + threadIdx.x;   // 1,048,576 total
    int b = idx >> 19;
    int rem = idx & 524287;                     // h[4] s[11] e4[4]
    int h = rem >> 15;
    int s = (rem >> 4) & 2047;
    int e0 = (rem & 15) * 4;
    size_t base = (((size_t)(b * 16 + h)) * 2048 + s) * 64 + e0;
    bf16x4 a = *(const bf16x4*)(Op0 + base);
    bf16x4 c = *(const bf16x4*)(Op1 + base);
    size_t li = ((size_t)(b * 16 + h)) * 2048 + s;
    float inv = 1.0f / (lacc[li] + lacc[65536 + li]);
    bf16x4 r;
#pragma unroll
    for (int j = 0; j < 4; ++j)
        r[j] = (__bf16)(((float)a[j] + (float)c[j]) * inv);
    *(bf16x4*)(x + ((size_t)b * 2048 + s) * 1024 + h * 64 + e0) = r;
}

// ---------------- launch ----------------

extern "C" void kernel_launch(void* const* d_in, const int* in_sizes, int n_in,
                              void* d_out, int out_size, void* d_ws, size_t ws_size,
                              hipStream_t stream) {
    const float* q    = (const float*)d_in[0];
    const float* k    = (const float*)d_in[1];
    const float* v    = (const float*)d_in[2];
    const float* mask = (const float*)d_in[3];
    const float* Wq   = (const float*)d_in[4];
    const float* bq   = (const float*)d_in[5];
    const float* Wk   = (const float*)d_in[6];
    const float* bk   = (const float*)d_in[7];
    const float* Wv   = (const float*)d_in[8];
    const float* bv   = (const float*)d_in[9];
    const float* Wo   = (const float*)d_in[10];
    const float* bo   = (const float*)d_in[11];

    char* ws = (char*)d_ws;
    __bf16* qb  = (__bf16*)(ws + (0ull  << 20));   // -> Op0 after gemm_qkv
    __bf16* kb  = (__bf16*)(ws + (8ull  << 20));   // -> Op1 after gemm_qkv
    __bf16* vb  = (__bf16*)(ws + (16ull << 20));   // -> x   after gemm_qkv
    __bf16* w3  = (__bf16*)(ws + (24ull << 20));   // 6 MB
    __bf16* wo  = (__bf16*)(ws + (30ull << 20));   // 2 MB (live till end)
    __bf16* Qpk = (__bf16*)(ws + (32ull << 20));   // packed Q
    __bf16* Kpk = (__bf16*)(ws + (40ull << 20));   // packed K
    __bf16* Vpk = (__bf16*)(ws + (48ull << 20));   // packed V
    float*  laccp = (float*)(ws + (56ull << 20));                        // 512 KB
    unsigned* flagp = (unsigned*)(ws + (56ull << 20) + (512ull << 10));  // 4 KB
    __bf16* Op0 = qb;
    __bf16* Op1 = kb;
    __bf16* xp  = vb;

    cvt3_kernel<<<dim3(4096, 3), 256, 0, stream>>>(q, k, v, qb, kb, vb);
    pack_wqkv<<<dim3(16, 16, 3), 256, 0, stream>>>(Wq, Wk, Wv, w3);
    pack_wo<<<dim3(16, 16), 256, 0, stream>>>(Wo, wo);
    hipMemsetAsync(flagp, 0, 4096, stream);
    mask_flags<<<8192, 256, 0, stream>>>(mask, flagp);

    gemm_qkv<<<dim3(32, 8, 3), 256, 0, stream>>>(qb, kb, vb, w3, bq, bk, bv,
                                                 Qpk, Kpk, Vpk);

    attn_kernel<<<dim3(1024), 256, 0, stream>>>(Qpk, Kpk, Vpk, mask, flagp,
                                                Op0, Op1, laccp);
    attn_norm<<<4096, 256, 0, stream>>>(Op0, Op1, laccp, xp);

    gemm_out<<<dim3(64, 8), 256, 0, stream>>>(xp, wo, bo, (float*)d_out);
}